// Round 11
// baseline (1254.666 us; speedup 1.0000x reference)
//
#include <hip/hip_runtime.h>
#include <hip/hip_fp16.h>

#define NPG 38
#define HEAD_BLK 256
#define SHIFT 14
#define SLICE (1 << SHIFT)        // 16384 nodes per dst-bucket (64KB LDS in binB)
#define DBMAX 320                 // max dst buckets
#define NSB 8                     // src super-buckets (== XCD count)
#define K1_NB 1024
#define P1_NB 4096
#define P1_THR 512
#define P1_QPB 3072               // max quads per P1 block (LDS stash bound)
#define CH 8192                   // records per P2 chunk (32KB LDS pairbuf)
#define P2_THR 512
#define P2_NW (P2_THR / 64)       // waves per P2 block

typedef int      v4i __attribute__((ext_vector_type(4)));
typedef float    v4f __attribute__((ext_vector_type(4)));
typedef unsigned v2u __attribute__((ext_vector_type(2)));

static inline __device__ unsigned short f2h(float f) {
    return __half_as_ushort(__float2half(f));
}
static inline __device__ float h2f(unsigned short b) {
    return __half2float(__ushort_as_half(b));
}

// ---------------------------------------------------------------------------
// K1: src super-bucket histogram only (dst histogram is fused into P1)
// ---------------------------------------------------------------------------
__global__ __launch_bounds__(512) void k_count8(
    const int* __restrict__ src, int nquads, int qpb, int sbsz,
    int* __restrict__ gcnt8)
{
    __shared__ int h8[NSB];
    if (threadIdx.x < NSB) h8[threadIdx.x] = 0;
    __syncthreads();
    const int q0 = blockIdx.x * qpb;
    const int q1 = min(q0 + qpb, nquads);
    const v4i* s4 = (const v4i*)src;
    for (int q = q0 + threadIdx.x; q < q1; q += 512) {
        v4i s = __builtin_nontemporal_load(s4 + q);
        atomicAdd(&h8[s.x / sbsz], 1);
        atomicAdd(&h8[s.y / sbsz], 1);
        atomicAdd(&h8[s.z / sbsz], 1);
        atomicAdd(&h8[s.w / sbsz], 1);
    }
    __syncthreads();
    if (threadIdx.x < NSB && h8[threadIdx.x])
        atomicAdd(&gcnt8[threadIdx.x], h8[threadIdx.x]);
}

// scan of the 8 super counts
__global__ void k_scan8(const int* __restrict__ gcnt8,
                        int* __restrict__ bbase8, int* __restrict__ gcur8)
{
    if (threadIdx.x == 0 && blockIdx.x == 0) {
        int run = 0;
        for (int i = 0; i < NSB; ++i) { bbase8[i] = run; gcur8[i] = run; run += gcnt8[i]; }
        bbase8[NSB] = run;
    }
}

// scan of dst-bucket counts (after P1 fills gcntD)
__global__ void k_scanD(const int* __restrict__ gcntD, int DB,
                        int* __restrict__ bbaseD, int* __restrict__ gcurD)
{
    if (threadIdx.x == 0 && blockIdx.x == 0) {
        int run = 0;
        for (int i = 0; i < DB; ++i) { bbaseD[i] = run; gcurD[i] = run; run += gcntD[i]; }
        bbaseD[DB] = run;
    }
}

// ---------------------------------------------------------------------------
// P1: route edges into 8 src-super segments; also accumulate dst-bucket
// histogram. Record = 8B:
//   lo = (src_local[15:0] << 16) | fp16(theta), hi = dst | (src_local[19:16]<<23)
// ---------------------------------------------------------------------------
__global__ __launch_bounds__(P1_THR) void k_p1(
    const int* __restrict__ src, const int* __restrict__ dst,
    const float* __restrict__ ea,
    const float* __restrict__ w_edge, const float* __restrict__ b_edge,
    int nquads, int qpb, int sbsz, int DB,
    int* __restrict__ gcur8, int* __restrict__ gcntD,
    v2u* __restrict__ recs)
{
    __shared__ v4i stash[P1_QPB];
    __shared__ int h8[NSB];
    __shared__ int cur8[NSB];
    __shared__ int hD[DBMAX];
    const int q0 = blockIdx.x * qpb;
    const int q1 = min(q0 + qpb, nquads);
    const int nq = q1 - q0;
    if (nq <= 0) return;
    if (threadIdx.x < NSB) h8[threadIdx.x] = 0;
    for (int i = threadIdx.x; i < DB; i += P1_THR) hD[i] = 0;
    __syncthreads();
    const v4i* s4 = (const v4i*)src;
    for (int j = threadIdx.x; j < nq; j += P1_THR) {
        v4i s = __builtin_nontemporal_load(s4 + q0 + j);
        stash[j] = s;
        atomicAdd(&h8[s.x / sbsz], 1);
        atomicAdd(&h8[s.y / sbsz], 1);
        atomicAdd(&h8[s.z / sbsz], 1);
        atomicAdd(&h8[s.w / sbsz], 1);
    }
    __syncthreads();
    if (threadIdx.x < NSB)
        cur8[threadIdx.x] = atomicAdd(&gcur8[threadIdx.x], h8[threadIdx.x]);
    __syncthreads();
    const float we = w_edge[0], be = b_edge[0];
    const v4i* d4 = (const v4i*)dst;
    const v4f* e4 = (const v4f*)ea;
    for (int j = threadIdx.x; j < nq; j += P1_THR) {
        v4i s = stash[j];
        v4i d = __builtin_nontemporal_load(d4 + q0 + j);
        v4f e = __builtin_nontemporal_load(e4 + q0 + j);
        #pragma unroll
        for (int k = 0; k < 4; ++k) {
            int sv = (k == 0) ? s.x : (k == 1) ? s.y : (k == 2) ? s.z : s.w;
            int dv = (k == 0) ? d.x : (k == 1) ? d.y : (k == 2) ? d.z : d.w;
            float ev = (k == 0) ? e.x : (k == 1) ? e.y : (k == 2) ? e.z : e.w;
            int sb = sv / sbsz;
            int sl = sv - sb * sbsz;
            unsigned short tb = f2h(fmaf(ev, we, be));
            atomicAdd(&hD[dv >> SHIFT], 1);
            int p = atomicAdd(&cur8[sb], 1);
            v2u r;
            r.x = ((unsigned)(sl & 0xFFFF) << 16) | (unsigned)tb;
            r.y = (unsigned)dv | ((unsigned)(sl >> 16) << 23);
            recs[p] = r;
        }
    }
    __syncthreads();
    for (int i = threadIdx.x; i < DB; i += P1_THR)
        if (hD[i]) atomicAdd(&gcntD[i], hD[i]);
}

// ---------------------------------------------------------------------------
// P2: per src-super chunk (sb = blockIdx&7 -> XCD affinity, x slice L2-hot).
// Counting sort: single shared histogram (R9 structure, 4 blocks/CU) +
// wave-0 shfl parallel exclusive scan (no serial tid0 section, no extra LDS).
// Pass C: per-wave coalesced run write-out.
// ---------------------------------------------------------------------------
__global__ __launch_bounds__(P2_THR) void k_p2(
    const v2u* __restrict__ recs, const float* __restrict__ x,
    const int* __restrict__ bbase8, int sbsz, int DB, int cpb,
    int* __restrict__ gcurD, unsigned* __restrict__ pairs)
{
    __shared__ unsigned pairbuf[CH];            // 32768 B
    __shared__ int hD[DBMAX];                   // bucket counts
    __shared__ int lofs[DBMAX];                 // local exclusive offsets
    __shared__ int lcur[DBMAX];                 // local running cursors
    __shared__ int gofs[DBMAX];                 // global reserved offsets

    const int sb = blockIdx.x & 7;
    const int c0 = blockIdx.x >> 3;
    const int seg0 = bbase8[sb], seg1 = bbase8[sb + 1];
    const float* xs = x + (size_t)sb * sbsz;
    const int tid = threadIdx.x;
    const int wid = tid >> 6, lane = tid & 63;

    for (int cc = c0; ; cc += cpb) {
        const int start = seg0 + cc * CH;
        if (start >= seg1) break;
        const int n = min(CH, seg1 - start);

        for (int i = tid; i < DBMAX; i += P2_THR) hD[i] = 0;
        __syncthreads();
        // pass A: histogram
        for (int i = tid; i < n; i += P2_THR) {
            v2u r = __builtin_nontemporal_load(recs + start + i);
            atomicAdd(&hD[(r.y & 0x7FFFFFu) >> SHIFT], 1);
        }
        __syncthreads();
        // wave 0: exclusive scan of hD[0..DBMAX) -> lofs (5 elems/lane + shfl)
        if (wid == 0) {
            const int base = lane * (DBMAX / 64);
            int vals[DBMAX / 64];
            int s = 0;
            #pragma unroll
            for (int k = 0; k < DBMAX / 64; ++k) { vals[k] = s; s += hD[base + k]; }
            int excl = s;
            #pragma unroll
            for (int d = 1; d < 64; d <<= 1) {
                int t = __shfl_up(excl, d, 64);
                if (lane >= d) excl += t;
            }
            excl -= s;
            #pragma unroll
            for (int k = 0; k < DBMAX / 64; ++k) lofs[base + k] = vals[k] + excl;
        }
        __syncthreads();
        // cursors + global reservation (parallel over buckets)
        for (int b = tid; b < DB; b += P2_THR) {
            lcur[b] = lofs[b];
            int cnt = hD[b];
            gofs[b] = cnt ? atomicAdd(&gcurD[b], cnt) : 0;
        }
        __syncthreads();
        // pass B: gather x (L2-resident slice), compute msg, LDS scatter-sort
        for (int i = tid; i < n; i += P2_THR) {
            v2u r = recs[start + i];                  // L2-hot re-read
            int sl = (int)(r.x >> 16) | (int)((r.y >> 23) << 16);
            unsigned d = r.y & 0x7FFFFFu;
            float m = xs[sl] * h2f((unsigned short)(r.x & 0xFFFFu));
            int li = atomicAdd(&lcur[d >> SHIFT], 1);
            pairbuf[li] = ((d & (SLICE - 1)) << 16) | (unsigned)f2h(m);
        }
        __syncthreads();
        // pass C: per-wave coalesced run write-out
        for (int b = wid; b < DB; b += P2_NW) {
            const int L = hD[b], lo = lofs[b], go = gofs[b];
            for (int j = lane; j < L; j += 64)
                pairs[go + j] = pairbuf[lo + j];
        }
        __syncthreads();
    }
}

// ---------------------------------------------------------------------------
// Mid-fallback: dst-binning with gather (reservation-based)
// ---------------------------------------------------------------------------
__global__ __launch_bounds__(512) void k_count_mid(
    const int* __restrict__ dst, int nquads, int qpb, int DB,
    int* __restrict__ gcntD)
{
    __shared__ int hD[DBMAX];
    for (int i = threadIdx.x; i < DB; i += 512) hD[i] = 0;
    __syncthreads();
    const int q0 = blockIdx.x * qpb;
    const int q1 = min(q0 + qpb, nquads);
    const v4i* d4 = (const v4i*)dst;
    for (int q = q0 + threadIdx.x; q < q1; q += 512) {
        v4i d = __builtin_nontemporal_load(d4 + q);
        atomicAdd(&hD[d.x >> SHIFT], 1);
        atomicAdd(&hD[d.y >> SHIFT], 1);
        atomicAdd(&hD[d.z >> SHIFT], 1);
        atomicAdd(&hD[d.w >> SHIFT], 1);
    }
    __syncthreads();
    for (int i = threadIdx.x; i < DB; i += 512)
        if (hD[i]) atomicAdd(&gcntD[i], hD[i]);
}

__global__ __launch_bounds__(512) void k_binA_resv(
    const float* __restrict__ x,
    const int* __restrict__ src, const int* __restrict__ dst,
    const float* __restrict__ ea,
    const float* __restrict__ w_edge, const float* __restrict__ b_edge,
    int nquads, int qpb, int DB,
    int* __restrict__ gcurD, unsigned* __restrict__ pairs)
{
    __shared__ int hD[DBMAX];
    __shared__ int cur[DBMAX];
    const int q0 = blockIdx.x * qpb;
    const int q1 = min(q0 + qpb, nquads);
    for (int i = threadIdx.x; i < DB; i += 512) hD[i] = 0;
    __syncthreads();
    const v4i* s4 = (const v4i*)src;
    const v4i* d4 = (const v4i*)dst;
    const v4f* e4 = (const v4f*)ea;
    for (int q = q0 + threadIdx.x; q < q1; q += 512) {
        v4i d = d4[q];
        atomicAdd(&hD[d.x >> SHIFT], 1);
        atomicAdd(&hD[d.y >> SHIFT], 1);
        atomicAdd(&hD[d.z >> SHIFT], 1);
        atomicAdd(&hD[d.w >> SHIFT], 1);
    }
    __syncthreads();
    for (int i = threadIdx.x; i < DB; i += 512) {
        int cnt = hD[i];
        cur[i] = cnt ? atomicAdd(&gcurD[i], cnt) : 0;
    }
    __syncthreads();
    const float we = w_edge[0], be = b_edge[0];
    for (int q = q0 + threadIdx.x; q < q1; q += 512) {
        v4i s = __builtin_nontemporal_load(s4 + q);
        v4i d = d4[q];
        v4f e = __builtin_nontemporal_load(e4 + q);
        #pragma unroll
        for (int k = 0; k < 4; ++k) {
            int sv = (k == 0) ? s.x : (k == 1) ? s.y : (k == 2) ? s.z : s.w;
            unsigned dv = (unsigned)((k == 0) ? d.x : (k == 1) ? d.y : (k == 2) ? d.z : d.w);
            float ev = (k == 0) ? e.x : (k == 1) ? e.y : (k == 2) ? e.z : e.w;
            float m = x[sv] * fmaf(ev, we, be);
            int p = atomicAdd(&cur[dv >> SHIFT], 1);
            pairs[p] = ((dv & (SLICE - 1)) << 16) | (unsigned)f2h(m);
        }
    }
}

// ---------------------------------------------------------------------------
// P3: per-bucket LDS accumulation of packed pairs + root transform -> nodes
// ---------------------------------------------------------------------------
__global__ __launch_bounds__(1024) void k_binB(
    const unsigned* __restrict__ pairs,
    const int* __restrict__ bbaseD,
    const float* __restrict__ x,
    const float* __restrict__ w_root, const float* __restrict__ b_conv,
    float* __restrict__ nodes, int N)
{
    __shared__ float slice[SLICE];               // 65536 B
    const int b = blockIdx.x;
    for (int i = threadIdx.x; i < SLICE; i += 1024) slice[i] = 0.0f;
    __syncthreads();
    const int p0 = bbaseD[b];
    const int p1 = bbaseD[b + 1];
    for (int i = p0 + threadIdx.x; i < p1; i += 1024) {
        unsigned p = __builtin_nontemporal_load(pairs + i);
        atomicAdd(&slice[p >> 16], h2f((unsigned short)(p & 0xFFFFu)));
    }
    __syncthreads();
    const float wr = w_root[0], bc = b_conv[0];
    const int gbase = b << SHIFT;
    for (int i = threadIdx.x; i < SLICE; i += 1024) {
        int gi = gbase + i;
        if (gi < N) nodes[gi] = slice[i] + fmaf(__builtin_nontemporal_load(x + gi), wr, bc);
    }
}

// ---------------------------------------------------------------------------
// Bottom fallback: global atomics
// ---------------------------------------------------------------------------
__global__ __launch_bounds__(256) void edge_kernel_atomic(
    const float* __restrict__ x,
    const int*   __restrict__ src, const int* __restrict__ dst,
    const float* __restrict__ ea,
    const float* __restrict__ w_edge, const float* __restrict__ b_edge,
    float* __restrict__ agg, int E)
{
    const float we = w_edge[0], be = b_edge[0];
    int tid = blockIdx.x * blockDim.x + threadIdx.x;
    int stride = gridDim.x * blockDim.x;
    for (int i = tid; i < E; i += stride)
        atomicAdd(&agg[dst[i]], x[src[i]] * fmaf(ea[i], we, be));
}

__global__ __launch_bounds__(256) void finalize_nodes(
    const float* __restrict__ x, const float* __restrict__ agg,
    const float* __restrict__ w_root, const float* __restrict__ b_conv,
    float* __restrict__ nodes, int N)
{
    const float wr = w_root[0], bc = b_conv[0];
    int i = blockIdx.x * blockDim.x + threadIdx.x;
    int stride = gridDim.x * blockDim.x;
    for (; i < N; i += stride) nodes[i] = agg[i] + fmaf(x[i], wr, bc);
}

// ---------------------------------------------------------------------------
// Head MLP over per-graph node vectors + softmax
// ---------------------------------------------------------------------------
__global__ __launch_bounds__(HEAD_BLK) void head_kernel(
    const float* __restrict__ nodes,
    const float* __restrict__ W1, const float* __restrict__ b1,
    const float* __restrict__ W2, const float* __restrict__ b2,
    const float* __restrict__ W3, const float* __restrict__ b3,
    float* __restrict__ out, int G)
{
    __shared__ float s_nodes[HEAD_BLK * NPG];   // 38912 B
    __shared__ float s_W1[NPG * 4];
    __shared__ float s_W2[4 * 4];
    __shared__ float s_W3[4 * 12];
    __shared__ float s_b1[4];
    __shared__ float s_b2[4];
    __shared__ float s_b3[12];

    const int tid = threadIdx.x;
    if (tid < NPG * 4) s_W1[tid] = W1[tid];
    if (tid >= 160 && tid < 176) s_W2[tid - 160] = W2[tid - 160];
    if (tid >= 176 && tid < 224) s_W3[tid - 176] = W3[tid - 176];
    if (tid >= 224 && tid < 228) s_b1[tid - 224] = b1[tid - 224];
    if (tid >= 228 && tid < 232) s_b2[tid - 228] = b2[tid - 228];
    if (tid >= 232 && tid < 244) s_b3[tid - 232] = b3[tid - 232];

    const int g0 = blockIdx.x * HEAD_BLK;
    const size_t ebase = (size_t)g0 * NPG;
    const int nelem = HEAD_BLK * NPG;
    const int avail = min(nelem, (G - g0) * NPG);
    for (int i = tid; i < avail; i += HEAD_BLK) s_nodes[i] = nodes[ebase + i];
    __syncthreads();

    const int g = g0 + tid;
    if (g >= G) return;
    const float* nd = &s_nodes[tid * NPG];

    float h1[4];
    #pragma unroll
    for (int k = 0; k < 4; ++k) h1[k] = s_b1[k];
    #pragma unroll
    for (int j = 0; j < NPG; ++j) {
        const float nj = nd[j];
        #pragma unroll
        for (int k = 0; k < 4; ++k) h1[k] = fmaf(nj, s_W1[j * 4 + k], h1[k]);
    }
    #pragma unroll
    for (int k = 0; k < 4; ++k) h1[k] = h1[k] >= 0.0f ? h1[k] : 0.01f * h1[k];

    float h2[4];
    #pragma unroll
    for (int k = 0; k < 4; ++k) {
        float a = s_b2[k];
        #pragma unroll
        for (int j = 0; j < 4; ++j) a = fmaf(h1[j], s_W2[j * 4 + k], a);
        h2[k] = a >= 0.0f ? a : 0.01f * a;
    }

    float h3[12];
    #pragma unroll
    for (int k = 0; k < 12; ++k) {
        float a = s_b3[k];
        #pragma unroll
        for (int j = 0; j < 4; ++j) a = fmaf(h2[j], s_W3[j * 12 + k], a);
        h3[k] = a >= 0.0f ? a : 0.01f * a;
    }

    float m = h3[0];
    #pragma unroll
    for (int k = 1; k < 12; ++k) m = fmaxf(m, h3[k]);
    float sum = 0.0f;
    #pragma unroll
    for (int k = 0; k < 12; ++k) { h3[k] = expf(h3[k] - m); sum += h3[k]; }
    const float inv = 1.0f / sum;

    float4* o = reinterpret_cast<float4*>(out + (size_t)g * 12);
    o[0] = make_float4(h3[0] * inv, h3[1] * inv, h3[2]  * inv, h3[3]  * inv);
    o[1] = make_float4(h3[4] * inv, h3[5] * inv, h3[6]  * inv, h3[7]  * inv);
    o[2] = make_float4(h3[8] * inv, h3[9] * inv, h3[10] * inv, h3[11] * inv);
}

extern "C" void kernel_launch(void* const* d_in, const int* in_sizes, int n_in,
                              void* d_out, int out_size, void* d_ws, size_t ws_size,
                              hipStream_t stream)
{
    const float* x      = (const float*)d_in[0];
    const int*   eidx   = (const int*)  d_in[1];
    const float* ea     = (const float*)d_in[2];
    const float* w_edge = (const float*)d_in[3];
    const float* b_edge = (const float*)d_in[4];
    const float* w_root = (const float*)d_in[5];
    const float* b_conv = (const float*)d_in[6];
    const float* W1 = (const float*)d_in[7];
    const float* b1 = (const float*)d_in[8];
    const float* W2 = (const float*)d_in[9];
    const float* b2 = (const float*)d_in[10];
    const float* W3 = (const float*)d_in[11];
    const float* b3 = (const float*)d_in[12];
    float* out = (float*)d_out;

    const int N = in_sizes[0];
    const int E = in_sizes[2];
    const int G = N / NPG;
    const int* src = eidx;
    const int* dst = eidx + E;
    const int nquads = E / 4;
    const int DB = (N + SLICE - 1) >> SHIFT;

    const int hblocks = (G + HEAD_BLK - 1) / HEAD_BLK;
    char* ws = (char*)d_ws;

    // meta ints: gcnt8[8], gcntD[DBMAX] | bbase8[9], gcur8[8],
    //            bbaseD[DBMAX+1], gcurD[DBMAX]
    const size_t META_INTS = 8 + DBMAX + 9 + 8 + (DBMAX + 1) + DBMAX;

    const bool quadok = (E % 4) == 0 && DB <= DBMAX && DB >= 1;
    const int  sbsz   = (N % NSB == 0) ? (N / NSB) : 0;
    const int  qpb1   = (nquads + P1_NB - 1) / P1_NB;

    // v3 layout: recs (E*8) | pairs (E*4) | nodes (N*4) | meta
    size_t off_pairs_v3 = (size_t)E * 8;
    size_t off_nodes_v3 = off_pairs_v3 + (size_t)E * 4;
    size_t off_meta_v3  = off_nodes_v3 + (size_t)N * 4;
    size_t need_v3      = off_meta_v3 + META_INTS * 4;

    // mid layout: pairs (E*4) | nodes | meta
    size_t off_nodes_mid = (size_t)E * 4;
    size_t off_meta_mid  = off_nodes_mid + (size_t)N * 4;
    size_t need_mid      = off_meta_mid + META_INTS * 4;

    if (quadok && sbsz > 0 && qpb1 <= P1_QPB && need_v3 <= ws_size) {
        v2u*      recs  = (v2u*)ws;
        unsigned* pairs = (unsigned*)(ws + off_pairs_v3);
        float*    nodes = (float*)(ws + off_nodes_v3);
        int*      meta  = (int*)(ws + off_meta_v3);
        int* gcnt8  = meta;
        int* gcntD  = meta + 8;
        int* bbase8 = meta + 8 + DBMAX;
        int* gcur8  = bbase8 + 9;
        int* bbaseD = gcur8 + 8;
        int* gcurD  = bbaseD + DBMAX + 1;

        hipMemsetAsync(meta, 0, (8 + DBMAX) * sizeof(int), stream);

        const int qpbK1 = (nquads + K1_NB - 1) / K1_NB;
        k_count8<<<K1_NB, 512, 0, stream>>>(src, nquads, qpbK1, sbsz, gcnt8);
        k_scan8<<<1, 64, 0, stream>>>(gcnt8, bbase8, gcur8);
        k_p1<<<P1_NB, P1_THR, 0, stream>>>(src, dst, ea, w_edge, b_edge,
                                           nquads, qpb1, sbsz, DB,
                                           gcur8, gcntD, recs);
        k_scanD<<<1, 64, 0, stream>>>(gcntD, DB, bbaseD, gcurD);
        const int cpb = (E + NSB * CH - 1) / (NSB * CH) + 64;  // grid-stride covers skew
        k_p2<<<NSB * cpb, P2_THR, 0, stream>>>(recs, x, bbase8, sbsz, DB, cpb,
                                               gcurD, pairs);
        k_binB<<<DB, 1024, 0, stream>>>(pairs, bbaseD, x, w_root, b_conv,
                                        nodes, N);
        head_kernel<<<hblocks, HEAD_BLK, 0, stream>>>(nodes, W1, b1, W2, b2,
                                                      W3, b3, out, G);
    } else if (quadok && need_mid <= ws_size) {
        unsigned* pairs = (unsigned*)ws;
        float*    nodes = (float*)(ws + off_nodes_mid);
        int*      meta  = (int*)(ws + off_meta_mid);
        int* gcntD  = meta + 8;
        int* bbaseD = meta + 8 + DBMAX + 9 + 8;
        int* gcurD  = bbaseD + DBMAX + 1;

        hipMemsetAsync(meta, 0, (8 + DBMAX) * sizeof(int), stream);
        const int NBm = 2048;
        const int qpbm = (nquads + NBm - 1) / NBm;
        k_count_mid<<<NBm, 512, 0, stream>>>(dst, nquads, qpbm, DB, gcntD);
        k_scanD<<<1, 64, 0, stream>>>(gcntD, DB, bbaseD, gcurD);
        k_binA_resv<<<NBm, 512, 0, stream>>>(x, src, dst, ea, w_edge, b_edge,
                                             nquads, qpbm, DB, gcurD, pairs);
        k_binB<<<DB, 1024, 0, stream>>>(pairs, bbaseD, x, w_root, b_conv,
                                        nodes, N);
        head_kernel<<<hblocks, HEAD_BLK, 0, stream>>>(nodes, W1, b1, W2, b2,
                                                      W3, b3, out, G);
    } else {
        float* agg   = (float*)d_ws;
        float* nodes = agg + N;
        hipMemsetAsync(agg, 0, (size_t)N * sizeof(float), stream);
        edge_kernel_atomic<<<2048, 256, 0, stream>>>(x, src, dst, ea, w_edge,
                                                     b_edge, agg, E);
        finalize_nodes<<<2048, 256, 0, stream>>>(x, agg, w_root, b_conv, nodes, N);
        head_kernel<<<hblocks, HEAD_BLK, 0, stream>>>(nodes, W1, b1, W2, b2,
                                                      W3, b3, out, G);
    }
}

// Round 12
// 1230.672 us; speedup vs baseline: 1.0195x; 1.0195x over previous
//
#include <hip/hip_runtime.h>
#include <hip/hip_fp16.h>

#define NPG 38
#define HEAD_BLK 256
#define SHIFT 14
#define SLICE (1 << SHIFT)        // 16384 nodes per dst-bucket (64KB LDS in binB)
#define DBMAX 320                 // max dst buckets
#define NSB 8                     // src super-buckets (== XCD count)
#define NB1 1024                  // blocks for P1a/P1b
#define P1_THR 512
#define CH 8192                   // records per P2 chunk (32KB LDS pairbuf)
#define P2_THR 512
#define P2_NW (P2_THR / 64)

typedef int      v4i __attribute__((ext_vector_type(4)));
typedef float    v4f __attribute__((ext_vector_type(4)));
typedef unsigned v2u __attribute__((ext_vector_type(2)));

static inline __device__ unsigned short f2h(float f) {
    return __half_as_ushort(__float2half(f));
}
static inline __device__ float h2f(unsigned short b) {
    return __half2float(__ushort_as_half(b));
}

// ---------------------------------------------------------------------------
// P1a: per-block per-super counts (plain store to histM8) + joint
// (super, dst-bucket) histogram flushed with NON-RETURNING atomics (posted).
// ---------------------------------------------------------------------------
__global__ __launch_bounds__(P1_THR) void k_p1a(
    const int* __restrict__ src, const int* __restrict__ dst,
    int nquads, int qpb, int sbsz, int DB,
    int* __restrict__ histM8,          // [NSB][NB1]
    int* __restrict__ gSD)             // [NSB][DBMAX]
{
    __shared__ int h8[NSB];
    __shared__ int hSD[NSB * DBMAX];   // 10240 B
    const int tid = threadIdx.x;
    if (tid < NSB) h8[tid] = 0;
    for (int i = tid; i < NSB * DBMAX; i += P1_THR) hSD[i] = 0;
    __syncthreads();
    const int blk = blockIdx.x;
    const int q0 = blk * qpb;
    const int q1 = min(q0 + qpb, nquads);
    const v4i* s4 = (const v4i*)src;
    const v4i* d4 = (const v4i*)dst;
    for (int q = q0 + tid; q < q1; q += P1_THR) {
        v4i s = __builtin_nontemporal_load(s4 + q);
        v4i d = __builtin_nontemporal_load(d4 + q);
        #pragma unroll
        for (int k = 0; k < 4; ++k) {
            int sv = (k == 0) ? s.x : (k == 1) ? s.y : (k == 2) ? s.z : s.w;
            int dv = (k == 0) ? d.x : (k == 1) ? d.y : (k == 2) ? d.z : d.w;
            int sb = sv / sbsz;
            atomicAdd(&h8[sb], 1);
            atomicAdd(&hSD[sb * DBMAX + (dv >> SHIFT)], 1);
        }
    }
    __syncthreads();
    if (tid < NSB) histM8[tid * NB1 + blk] = h8[tid];          // plain store
    for (int i = tid; i < NSB * DBMAX; i += P1_THR)
        if (hSD[i]) atomicAdd(&gSD[i], hSD[i]);                // posted, no return
}

// ---------------------------------------------------------------------------
// Scan meta: histM8 -> absolute per-block emit offsets (in place);
// gSD -> bbaseD[DB+1] and per-(super,bucket) cursors gcurSD.
// Single block, 512 threads, wave-parallel scans. No serial global chains.
// ---------------------------------------------------------------------------
__global__ __launch_bounds__(512) void k_scan_meta(
    int* __restrict__ histM8,          // [NSB][NB1] in: counts, out: offsets
    const int* __restrict__ gSD,       // [NSB][DBMAX]
    int DB,
    int* __restrict__ gcurSD,          // [NSB][DBMAX] out
    int* __restrict__ bbaseD)          // [DBMAX+1]    out
{
    __shared__ int stot[NSB];
    __shared__ int sbase[NSB + 1];
    __shared__ int btot[DBMAX];
    __shared__ int bof[DBMAX];
    const int tid = threadIdx.x;
    const int wid = tid >> 6, lane = tid & 63;

    // per-super scan of histM8 rows: wave w handles super w (16 elems/lane)
    {
        const int base = wid * NB1 + lane * (NB1 / 64);
        int vals[NB1 / 64];
        int s = 0;
        #pragma unroll
        for (int k = 0; k < NB1 / 64; ++k) { vals[k] = s; s += histM8[base + k]; }
        int excl = s;
        #pragma unroll
        for (int d = 1; d < 64; d <<= 1) {
            int t = __shfl_up(excl, d, 64);
            if (lane >= d) excl += t;
        }
        excl -= s;
        if (lane == 63) stot[wid] = excl + s;
        __syncthreads();
        if (tid == 0) {
            int run = 0;
            for (int i = 0; i < NSB; ++i) { sbase[i] = run; run += stot[i]; }
            sbase[NSB] = run;
        }
        __syncthreads();
        const int b0 = sbase[wid] + excl;
        #pragma unroll
        for (int k = 0; k < NB1 / 64; ++k) histM8[base + k] = vals[k] + b0;
    }
    __syncthreads();
    // bucket totals over supers
    for (int b = tid; b < DBMAX; b += 512) {
        int s = 0;
        if (b < DB) {
            #pragma unroll
            for (int w = 0; w < NSB; ++w) s += gSD[w * DBMAX + b];
        }
        btot[b] = s;
    }
    __syncthreads();
    // wave 0: exclusive scan of btot -> bof (5 elems/lane)
    if (wid == 0) {
        const int base = lane * (DBMAX / 64);
        int vals[DBMAX / 64];
        int s = 0;
        #pragma unroll
        for (int k = 0; k < DBMAX / 64; ++k) { vals[k] = s; s += btot[base + k]; }
        int excl = s;
        #pragma unroll
        for (int d = 1; d < 64; d <<= 1) {
            int t = __shfl_up(excl, d, 64);
            if (lane >= d) excl += t;
        }
        excl -= s;
        #pragma unroll
        for (int k = 0; k < DBMAX / 64; ++k) bof[base + k] = vals[k] + excl;
    }
    __syncthreads();
    // bbaseD + per-(super,bucket) cursor bases
    for (int b = tid; b < DB; b += 512) {
        bbaseD[b] = bof[b];
        int run = bof[b];
        #pragma unroll
        for (int w = 0; w < NSB; ++w) {
            gcurSD[w * DBMAX + b] = run;
            run += gSD[w * DBMAX + b];
        }
    }
    if (tid == 0) bbaseD[DB] = bof[DB - 1] + btot[DB - 1];
}

// scan of dst-bucket counts (mid-fallback path)
__global__ void k_scanD(const int* __restrict__ gcntD, int DB,
                        int* __restrict__ bbaseD, int* __restrict__ gcurD)
{
    if (threadIdx.x == 0 && blockIdx.x == 0) {
        int run = 0;
        for (int i = 0; i < DB; ++i) { bbaseD[i] = run; gcurD[i] = run; run += gcntD[i]; }
        bbaseD[DB] = run;
    }
}

// ---------------------------------------------------------------------------
// P1b: re-read edges, emit records at PRECOMPUTED absolute offsets (LDS-only
// cursors, zero global returning atomics). Record = 8B:
//   lo = (src_local[15:0] << 16) | fp16(theta), hi = dst | (src_local[19:16]<<23)
// ---------------------------------------------------------------------------
__global__ __launch_bounds__(P1_THR) void k_p1b(
    const int* __restrict__ src, const int* __restrict__ dst,
    const float* __restrict__ ea,
    const float* __restrict__ w_edge, const float* __restrict__ b_edge,
    int nquads, int qpb, int sbsz,
    const int* __restrict__ histM8,    // absolute offsets per (super, block)
    v2u* __restrict__ recs)
{
    __shared__ int cur8[NSB];
    const int blk = blockIdx.x;
    if (threadIdx.x < NSB) cur8[threadIdx.x] = histM8[threadIdx.x * NB1 + blk];
    __syncthreads();
    const int q0 = blk * qpb;
    const int q1 = min(q0 + qpb, nquads);
    const float we = w_edge[0], be = b_edge[0];
    const v4i* s4 = (const v4i*)src;
    const v4i* d4 = (const v4i*)dst;
    const v4f* e4 = (const v4f*)ea;
    for (int q = q0 + threadIdx.x; q < q1; q += P1_THR) {
        v4i s = __builtin_nontemporal_load(s4 + q);
        v4i d = __builtin_nontemporal_load(d4 + q);
        v4f e = __builtin_nontemporal_load(e4 + q);
        #pragma unroll
        for (int k = 0; k < 4; ++k) {
            int sv = (k == 0) ? s.x : (k == 1) ? s.y : (k == 2) ? s.z : s.w;
            int dv = (k == 0) ? d.x : (k == 1) ? d.y : (k == 2) ? d.z : d.w;
            float ev = (k == 0) ? e.x : (k == 1) ? e.y : (k == 2) ? e.z : e.w;
            int sb = sv / sbsz;
            int sl = sv - sb * sbsz;
            unsigned short tb = f2h(fmaf(ev, we, be));
            int p = atomicAdd(&cur8[sb], 1);       // LDS-only
            v2u r;
            r.x = ((unsigned)(sl & 0xFFFF) << 16) | (unsigned)tb;
            r.y = (unsigned)dv | ((unsigned)(sl >> 16) << 23);
            recs[p] = r;
        }
    }
}

// ---------------------------------------------------------------------------
// P2: per src-super chunk (sb = blockIdx&7 -> XCD affinity, x slice L2-hot).
// Counting sort; reservation on PER-SUPER cursors gcurSD (8x shallower
// returning-atomic chains, XCD-local lines). Pass C: coalesced run write-out.
// ---------------------------------------------------------------------------
__global__ __launch_bounds__(P2_THR) void k_p2(
    const v2u* __restrict__ recs, const float* __restrict__ x,
    const int* __restrict__ histM8_unused, int sbsz, int DB, int cpb,
    const int* __restrict__ sseg,      // segment bases: sseg[s] = start of super s
    int* __restrict__ gcurSD, unsigned* __restrict__ pairs)
{
    __shared__ unsigned pairbuf[CH];            // 32768 B
    __shared__ int hD[DBMAX];
    __shared__ int lofs[DBMAX];
    __shared__ int lcur[DBMAX];
    __shared__ int gofs[DBMAX];

    const int sb = blockIdx.x & 7;
    const int c0 = blockIdx.x >> 3;
    const int seg0 = sseg[sb], seg1 = sseg[sb + 1];
    const float* xs = x + (size_t)sb * sbsz;
    const int tid = threadIdx.x;
    const int wid = tid >> 6, lane = tid & 63;
    int* gcur = gcurSD + sb * DBMAX;

    for (int cc = c0; ; cc += cpb) {
        const int start = seg0 + cc * CH;
        if (start >= seg1) break;
        const int n = min(CH, seg1 - start);

        for (int i = tid; i < DBMAX; i += P2_THR) hD[i] = 0;
        __syncthreads();
        // pass A: histogram
        for (int i = tid; i < n; i += P2_THR) {
            v2u r = __builtin_nontemporal_load(recs + start + i);
            atomicAdd(&hD[(r.y & 0x7FFFFFu) >> SHIFT], 1);
        }
        __syncthreads();
        // wave 0: exclusive scan of hD -> lofs
        if (wid == 0) {
            const int base = lane * (DBMAX / 64);
            int vals[DBMAX / 64];
            int s = 0;
            #pragma unroll
            for (int k = 0; k < DBMAX / 64; ++k) { vals[k] = s; s += hD[base + k]; }
            int excl = s;
            #pragma unroll
            for (int d = 1; d < 64; d <<= 1) {
                int t = __shfl_up(excl, d, 64);
                if (lane >= d) excl += t;
            }
            excl -= s;
            #pragma unroll
            for (int k = 0; k < DBMAX / 64; ++k) lofs[base + k] = vals[k] + excl;
        }
        __syncthreads();
        // cursors + per-super global reservation
        for (int b = tid; b < DB; b += P2_THR) {
            lcur[b] = lofs[b];
            int cnt = hD[b];
            gofs[b] = cnt ? atomicAdd(&gcur[b], cnt) : 0;
        }
        __syncthreads();
        // pass B: gather x (L2-resident slice), LDS scatter-sort
        for (int i = tid; i < n; i += P2_THR) {
            v2u r = recs[start + i];                  // L2-hot re-read
            int sl = (int)(r.x >> 16) | (int)((r.y >> 23) << 16);
            unsigned d = r.y & 0x7FFFFFu;
            float m = xs[sl] * h2f((unsigned short)(r.x & 0xFFFFu));
            int li = atomicAdd(&lcur[d >> SHIFT], 1);
            pairbuf[li] = ((d & (SLICE - 1)) << 16) | (unsigned)f2h(m);
        }
        __syncthreads();
        // pass C: per-wave coalesced run write-out
        for (int b = wid; b < DB; b += P2_NW) {
            const int L = hD[b], lo = lofs[b], go = gofs[b];
            for (int j = lane; j < L; j += 64)
                pairs[go + j] = pairbuf[lo + j];
        }
        __syncthreads();
    }
}

// segment bases for P2 from histM8 row starts (sseg[s] = histM8[s*NB1 + 0])
__global__ void k_sseg(const int* __restrict__ histM8, int* __restrict__ sseg, int total)
{
    if (threadIdx.x == 0 && blockIdx.x == 0) {
        for (int s = 0; s < NSB; ++s) sseg[s] = histM8[s * NB1];
        sseg[NSB] = total;
    }
}

// ---------------------------------------------------------------------------
// Mid-fallback: dst-binning with gather (reservation-based)
// ---------------------------------------------------------------------------
__global__ __launch_bounds__(512) void k_count_mid(
    const int* __restrict__ dst, int nquads, int qpb, int DB,
    int* __restrict__ gcntD)
{
    __shared__ int hD[DBMAX];
    for (int i = threadIdx.x; i < DB; i += 512) hD[i] = 0;
    __syncthreads();
    const int q0 = blockIdx.x * qpb;
    const int q1 = min(q0 + qpb, nquads);
    const v4i* d4 = (const v4i*)dst;
    for (int q = q0 + threadIdx.x; q < q1; q += 512) {
        v4i d = __builtin_nontemporal_load(d4 + q);
        atomicAdd(&hD[d.x >> SHIFT], 1);
        atomicAdd(&hD[d.y >> SHIFT], 1);
        atomicAdd(&hD[d.z >> SHIFT], 1);
        atomicAdd(&hD[d.w >> SHIFT], 1);
    }
    __syncthreads();
    for (int i = threadIdx.x; i < DB; i += 512)
        if (hD[i]) atomicAdd(&gcntD[i], hD[i]);
}

__global__ __launch_bounds__(512) void k_binA_resv(
    const float* __restrict__ x,
    const int* __restrict__ src, const int* __restrict__ dst,
    const float* __restrict__ ea,
    const float* __restrict__ w_edge, const float* __restrict__ b_edge,
    int nquads, int qpb, int DB,
    int* __restrict__ gcurD, unsigned* __restrict__ pairs)
{
    __shared__ int hD[DBMAX];
    __shared__ int cur[DBMAX];
    const int q0 = blockIdx.x * qpb;
    const int q1 = min(q0 + qpb, nquads);
    for (int i = threadIdx.x; i < DB; i += 512) hD[i] = 0;
    __syncthreads();
    const v4i* s4 = (const v4i*)src;
    const v4i* d4 = (const v4i*)dst;
    const v4f* e4 = (const v4f*)ea;
    for (int q = q0 + threadIdx.x; q < q1; q += 512) {
        v4i d = d4[q];
        atomicAdd(&hD[d.x >> SHIFT], 1);
        atomicAdd(&hD[d.y >> SHIFT], 1);
        atomicAdd(&hD[d.z >> SHIFT], 1);
        atomicAdd(&hD[d.w >> SHIFT], 1);
    }
    __syncthreads();
    for (int i = threadIdx.x; i < DB; i += 512) {
        int cnt = hD[i];
        cur[i] = cnt ? atomicAdd(&gcurD[i], cnt) : 0;
    }
    __syncthreads();
    const float we = w_edge[0], be = b_edge[0];
    for (int q = q0 + threadIdx.x; q < q1; q += 512) {
        v4i s = __builtin_nontemporal_load(s4 + q);
        v4i d = d4[q];
        v4f e = __builtin_nontemporal_load(e4 + q);
        #pragma unroll
        for (int k = 0; k < 4; ++k) {
            int sv = (k == 0) ? s.x : (k == 1) ? s.y : (k == 2) ? s.z : s.w;
            unsigned dv = (unsigned)((k == 0) ? d.x : (k == 1) ? d.y : (k == 2) ? d.z : d.w);
            float ev = (k == 0) ? e.x : (k == 1) ? e.y : (k == 2) ? e.z : e.w;
            float m = x[sv] * fmaf(ev, we, be);
            int p = atomicAdd(&cur[dv >> SHIFT], 1);
            pairs[p] = ((dv & (SLICE - 1)) << 16) | (unsigned)f2h(m);
        }
    }
}

// ---------------------------------------------------------------------------
// P3: per-bucket LDS accumulation of packed pairs + root transform -> nodes
// ---------------------------------------------------------------------------
__global__ __launch_bounds__(1024) void k_binB(
    const unsigned* __restrict__ pairs,
    const int* __restrict__ bbaseD,
    const float* __restrict__ x,
    const float* __restrict__ w_root, const float* __restrict__ b_conv,
    float* __restrict__ nodes, int N)
{
    __shared__ float slice[SLICE];               // 65536 B
    const int b = blockIdx.x;
    for (int i = threadIdx.x; i < SLICE; i += 1024) slice[i] = 0.0f;
    __syncthreads();
    const int p0 = bbaseD[b];
    const int p1 = bbaseD[b + 1];
    for (int i = p0 + threadIdx.x; i < p1; i += 1024) {
        unsigned p = __builtin_nontemporal_load(pairs + i);
        atomicAdd(&slice[p >> 16], h2f((unsigned short)(p & 0xFFFFu)));
    }
    __syncthreads();
    const float wr = w_root[0], bc = b_conv[0];
    const int gbase = b << SHIFT;
    for (int i = threadIdx.x; i < SLICE; i += 1024) {
        int gi = gbase + i;
        if (gi < N) nodes[gi] = slice[i] + fmaf(__builtin_nontemporal_load(x + gi), wr, bc);
    }
}

// ---------------------------------------------------------------------------
// Bottom fallback: global atomics
// ---------------------------------------------------------------------------
__global__ __launch_bounds__(256) void edge_kernel_atomic(
    const float* __restrict__ x,
    const int*   __restrict__ src, const int* __restrict__ dst,
    const float* __restrict__ ea,
    const float* __restrict__ w_edge, const float* __restrict__ b_edge,
    float* __restrict__ agg, int E)
{
    const float we = w_edge[0], be = b_edge[0];
    int tid = blockIdx.x * blockDim.x + threadIdx.x;
    int stride = gridDim.x * blockDim.x;
    for (int i = tid; i < E; i += stride)
        atomicAdd(&agg[dst[i]], x[src[i]] * fmaf(ea[i], we, be));
}

__global__ __launch_bounds__(256) void finalize_nodes(
    const float* __restrict__ x, const float* __restrict__ agg,
    const float* __restrict__ w_root, const float* __restrict__ b_conv,
    float* __restrict__ nodes, int N)
{
    const float wr = w_root[0], bc = b_conv[0];
    int i = blockIdx.x * blockDim.x + threadIdx.x;
    int stride = gridDim.x * blockDim.x;
    for (; i < N; i += stride) nodes[i] = agg[i] + fmaf(x[i], wr, bc);
}

// ---------------------------------------------------------------------------
// Head MLP over per-graph node vectors + softmax
// ---------------------------------------------------------------------------
__global__ __launch_bounds__(HEAD_BLK) void head_kernel(
    const float* __restrict__ nodes,
    const float* __restrict__ W1, const float* __restrict__ b1,
    const float* __restrict__ W2, const float* __restrict__ b2,
    const float* __restrict__ W3, const float* __restrict__ b3,
    float* __restrict__ out, int G)
{
    __shared__ float s_nodes[HEAD_BLK * NPG];   // 38912 B
    __shared__ float s_W1[NPG * 4];
    __shared__ float s_W2[4 * 4];
    __shared__ float s_W3[4 * 12];
    __shared__ float s_b1[4];
    __shared__ float s_b2[4];
    __shared__ float s_b3[12];

    const int tid = threadIdx.x;
    if (tid < NPG * 4) s_W1[tid] = W1[tid];
    if (tid >= 160 && tid < 176) s_W2[tid - 160] = W2[tid - 160];
    if (tid >= 176 && tid < 224) s_W3[tid - 176] = W3[tid - 176];
    if (tid >= 224 && tid < 228) s_b1[tid - 224] = b1[tid - 224];
    if (tid >= 228 && tid < 232) s_b2[tid - 228] = b2[tid - 228];
    if (tid >= 232 && tid < 244) s_b3[tid - 232] = b3[tid - 232];

    const int g0 = blockIdx.x * HEAD_BLK;
    const size_t ebase = (size_t)g0 * NPG;
    const int nelem = HEAD_BLK * NPG;
    const int avail = min(nelem, (G - g0) * NPG);
    for (int i = tid; i < avail; i += HEAD_BLK) s_nodes[i] = nodes[ebase + i];
    __syncthreads();

    const int g = g0 + tid;
    if (g >= G) return;
    const float* nd = &s_nodes[tid * NPG];

    float h1[4];
    #pragma unroll
    for (int k = 0; k < 4; ++k) h1[k] = s_b1[k];
    #pragma unroll
    for (int j = 0; j < NPG; ++j) {
        const float nj = nd[j];
        #pragma unroll
        for (int k = 0; k < 4; ++k) h1[k] = fmaf(nj, s_W1[j * 4 + k], h1[k]);
    }
    #pragma unroll
    for (int k = 0; k < 4; ++k) h1[k] = h1[k] >= 0.0f ? h1[k] : 0.01f * h1[k];

    float h2[4];
    #pragma unroll
    for (int k = 0; k < 4; ++k) {
        float a = s_b2[k];
        #pragma unroll
        for (int j = 0; j < 4; ++j) a = fmaf(h1[j], s_W2[j * 4 + k], a);
        h2[k] = a >= 0.0f ? a : 0.01f * a;
    }

    float h3[12];
    #pragma unroll
    for (int k = 0; k < 12; ++k) {
        float a = s_b3[k];
        #pragma unroll
        for (int j = 0; j < 4; ++j) a = fmaf(h2[j], s_W3[j * 12 + k], a);
        h3[k] = a >= 0.0f ? a : 0.01f * a;
    }

    float m = h3[0];
    #pragma unroll
    for (int k = 1; k < 12; ++k) m = fmaxf(m, h3[k]);
    float sum = 0.0f;
    #pragma unroll
    for (int k = 0; k < 12; ++k) { h3[k] = expf(h3[k] - m); sum += h3[k]; }
    const float inv = 1.0f / sum;

    float4* o = reinterpret_cast<float4*>(out + (size_t)g * 12);
    o[0] = make_float4(h3[0] * inv, h3[1] * inv, h3[2]  * inv, h3[3]  * inv);
    o[1] = make_float4(h3[4] * inv, h3[5] * inv, h3[6]  * inv, h3[7]  * inv);
    o[2] = make_float4(h3[8] * inv, h3[9] * inv, h3[10] * inv, h3[11] * inv);
}

extern "C" void kernel_launch(void* const* d_in, const int* in_sizes, int n_in,
                              void* d_out, int out_size, void* d_ws, size_t ws_size,
                              hipStream_t stream)
{
    const float* x      = (const float*)d_in[0];
    const int*   eidx   = (const int*)  d_in[1];
    const float* ea     = (const float*)d_in[2];
    const float* w_edge = (const float*)d_in[3];
    const float* b_edge = (const float*)d_in[4];
    const float* w_root = (const float*)d_in[5];
    const float* b_conv = (const float*)d_in[6];
    const float* W1 = (const float*)d_in[7];
    const float* b1 = (const float*)d_in[8];
    const float* W2 = (const float*)d_in[9];
    const float* b2 = (const float*)d_in[10];
    const float* W3 = (const float*)d_in[11];
    const float* b3 = (const float*)d_in[12];
    float* out = (float*)d_out;

    const int N = in_sizes[0];
    const int E = in_sizes[2];
    const int G = N / NPG;
    const int* src = eidx;
    const int* dst = eidx + E;
    const int nquads = E / 4;
    const int DB = (N + SLICE - 1) >> SHIFT;

    const int hblocks = (G + HEAD_BLK - 1) / HEAD_BLK;
    char* ws = (char*)d_ws;

    // meta ints: gSD[NSB*DBMAX] | gcurSD[NSB*DBMAX] | bbaseD[DBMAX+1] |
    //            sseg[NSB+1] | gcntD[DBMAX] | gcurD[DBMAX] | histM8[NSB*NB1]
    const size_t N_GSD   = NSB * DBMAX;
    const size_t N_HISTM = NSB * NB1;
    const size_t META_INTS = N_GSD + N_GSD + (DBMAX + 1) + (NSB + 1)
                           + DBMAX + DBMAX + N_HISTM;

    const bool quadok = (E % 4) == 0 && DB <= DBMAX && DB >= 1;
    const int  sbsz   = (N % NSB == 0) ? (N / NSB) : 0;

    // v3 layout: recs (E*8) | pairs (E*4) | nodes (N*4) | meta
    size_t off_pairs_v3 = (size_t)E * 8;
    size_t off_nodes_v3 = off_pairs_v3 + (size_t)E * 4;
    size_t off_meta_v3  = off_nodes_v3 + (size_t)N * 4;
    size_t need_v3      = off_meta_v3 + META_INTS * 4;

    // mid layout: pairs (E*4) | nodes | meta
    size_t off_nodes_mid = (size_t)E * 4;
    size_t off_meta_mid  = off_nodes_mid + (size_t)N * 4;
    size_t need_mid      = off_meta_mid + META_INTS * 4;

    if (quadok && sbsz > 0 && need_v3 <= ws_size) {
        v2u*      recs  = (v2u*)ws;
        unsigned* pairs = (unsigned*)(ws + off_pairs_v3);
        float*    nodes = (float*)(ws + off_nodes_v3);
        int*      meta  = (int*)(ws + off_meta_v3);
        int* gSD    = meta;
        int* gcurSD = gSD + N_GSD;
        int* bbaseD = gcurSD + N_GSD;
        int* sseg   = bbaseD + DBMAX + 1;
        int* histM8 = sseg + (NSB + 1) + DBMAX + DBMAX;

        hipMemsetAsync(gSD, 0, N_GSD * sizeof(int), stream);

        const int qpb = (nquads + NB1 - 1) / NB1;
        k_p1a<<<NB1, P1_THR, 0, stream>>>(src, dst, nquads, qpb, sbsz, DB,
                                          histM8, gSD);
        k_scan_meta<<<1, 512, 0, stream>>>(histM8, gSD, DB, gcurSD, bbaseD);
        k_sseg<<<1, 64, 0, stream>>>(histM8, sseg, E);
        k_p1b<<<NB1, P1_THR, 0, stream>>>(src, dst, ea, w_edge, b_edge,
                                          nquads, qpb, sbsz, histM8, recs);
        const int cpb = (E + NSB * CH - 1) / (NSB * CH) + 64;
        k_p2<<<NSB * cpb, P2_THR, 0, stream>>>(recs, x, histM8, sbsz, DB, cpb,
                                               sseg, gcurSD, pairs);
        k_binB<<<DB, 1024, 0, stream>>>(pairs, bbaseD, x, w_root, b_conv,
                                        nodes, N);
        head_kernel<<<hblocks, HEAD_BLK, 0, stream>>>(nodes, W1, b1, W2, b2,
                                                      W3, b3, out, G);
    } else if (quadok && need_mid <= ws_size) {
        unsigned* pairs = (unsigned*)ws;
        float*    nodes = (float*)(ws + off_nodes_mid);
        int*      meta  = (int*)(ws + off_meta_mid);
        int* bbaseD = meta + N_GSD + N_GSD;
        int* gcntD  = bbaseD + DBMAX + 1 + (NSB + 1);
        int* gcurD  = gcntD + DBMAX;

        hipMemsetAsync(gcntD, 0, DBMAX * sizeof(int), stream);
        const int NBm = 2048;
        const int qpbm = (nquads + NBm - 1) / NBm;
        k_count_mid<<<NBm, 512, 0, stream>>>(dst, nquads, qpbm, DB, gcntD);
        k_scanD<<<1, 64, 0, stream>>>(gcntD, DB, bbaseD, gcurD);
        k_binA_resv<<<NBm, 512, 0, stream>>>(x, src, dst, ea, w_edge, b_edge,
                                             nquads, qpbm, DB, gcurD, pairs);
        k_binB<<<DB, 1024, 0, stream>>>(pairs, bbaseD, x, w_root, b_conv,
                                        nodes, N);
        head_kernel<<<hblocks, HEAD_BLK, 0, stream>>>(nodes, W1, b1, W2, b2,
                                                      W3, b3, out, G);
    } else {
        float* agg   = (float*)d_ws;
        float* nodes = agg + N;
        hipMemsetAsync(agg, 0, (size_t)N * sizeof(float), stream);
        edge_kernel_atomic<<<2048, 256, 0, stream>>>(x, src, dst, ea, w_edge,
                                                     b_edge, agg, E);
        finalize_nodes<<<2048, 256, 0, stream>>>(x, agg, w_root, b_conv, nodes, N);
        head_kernel<<<hblocks, HEAD_BLK, 0, stream>>>(nodes, W1, b1, W2, b2,
                                                      W3, b3, out, G);
    }
}

// Round 13
// 1171.654 us; speedup vs baseline: 1.0709x; 1.0504x over previous
//
#include <hip/hip_runtime.h>
#include <hip/hip_fp16.h>

#define NPG 38
#define HEAD_BLK 256
#define SHIFT 14
#define SLICE (1 << SHIFT)        // 16384 nodes per dst-bucket (64KB LDS in binB)
#define DBMAX 320                 // max dst buckets
#define NSB 8                     // src super-buckets (== XCD count)
#define NB1 1024                  // blocks for P1a/P1b
#define P1_THR 512
#define CH 8192                   // records per P2 chunk
#define P2_THR 512

typedef int      v4i __attribute__((ext_vector_type(4)));
typedef float    v4f __attribute__((ext_vector_type(4)));
typedef unsigned v2u __attribute__((ext_vector_type(2)));

static inline __device__ unsigned short f2h(float f) {
    return __half_as_ushort(__float2half(f));
}
static inline __device__ float h2f(unsigned short b) {
    return __half2float(__ushort_as_half(b));
}

// ---------------------------------------------------------------------------
// P1a: per-block per-super counts only (src read only; plain stores).
// ---------------------------------------------------------------------------
__global__ __launch_bounds__(P1_THR) void k_p1a(
    const int* __restrict__ src, int nquads, int qpb, int sbsz,
    int* __restrict__ histM8)          // [NSB][NB1]
{
    __shared__ int h8[NSB];
    const int tid = threadIdx.x;
    if (tid < NSB) h8[tid] = 0;
    __syncthreads();
    const int blk = blockIdx.x;
    const int q0 = blk * qpb;
    const int q1 = min(q0 + qpb, nquads);
    const v4i* s4 = (const v4i*)src;
    for (int q = q0 + tid; q < q1; q += P1_THR) {
        v4i s = __builtin_nontemporal_load(s4 + q);
        atomicAdd(&h8[s.x / sbsz], 1);
        atomicAdd(&h8[s.y / sbsz], 1);
        atomicAdd(&h8[s.z / sbsz], 1);
        atomicAdd(&h8[s.w / sbsz], 1);
    }
    __syncthreads();
    if (tid < NSB) histM8[tid * NB1 + blk] = h8[tid];
}

// ---------------------------------------------------------------------------
// scanM: histM8 -> absolute per-(super,block) emit offsets (in place) + sseg.
// Wave w scans row w (16 elems/lane + shfl). Single block.
// ---------------------------------------------------------------------------
__global__ __launch_bounds__(512) void k_scanM(
    int* __restrict__ histM8, int* __restrict__ sseg)
{
    __shared__ int stot[NSB];
    __shared__ int sbase[NSB + 1];
    const int tid = threadIdx.x;
    const int wid = tid >> 6, lane = tid & 63;

    const int base = wid * NB1 + lane * (NB1 / 64);
    int vals[NB1 / 64];
    int s = 0;
    #pragma unroll
    for (int k = 0; k < NB1 / 64; ++k) { vals[k] = s; s += histM8[base + k]; }
    int excl = s;
    #pragma unroll
    for (int d = 1; d < 64; d <<= 1) {
        int t = __shfl_up(excl, d, 64);
        if (lane >= d) excl += t;
    }
    excl -= s;
    if (lane == 63) stot[wid] = excl + s;
    __syncthreads();
    if (tid == 0) {
        int run = 0;
        for (int i = 0; i < NSB; ++i) { sbase[i] = run; run += stot[i]; }
        sbase[NSB] = run;
    }
    __syncthreads();
    const int b0 = sbase[wid] + excl;
    #pragma unroll
    for (int k = 0; k < NB1 / 64; ++k) histM8[base + k] = vals[k] + b0;
    if (tid < NSB + 1) sseg[tid] = sbase[tid];
}

// ---------------------------------------------------------------------------
// P1b: re-read edges, emit records at precomputed absolute offsets.
// Record = 8B: lo = (src_local[15:0]<<16)|fp16(theta), hi = dst|(sl>>16)<<23
// ---------------------------------------------------------------------------
__global__ __launch_bounds__(P1_THR) void k_p1b(
    const int* __restrict__ src, const int* __restrict__ dst,
    const float* __restrict__ ea,
    const float* __restrict__ w_edge, const float* __restrict__ b_edge,
    int nquads, int qpb, int sbsz,
    const int* __restrict__ histM8,
    v2u* __restrict__ recs)
{
    __shared__ int cur8[NSB];
    const int blk = blockIdx.x;
    if (threadIdx.x < NSB) cur8[threadIdx.x] = histM8[threadIdx.x * NB1 + blk];
    __syncthreads();
    const int q0 = blk * qpb;
    const int q1 = min(q0 + qpb, nquads);
    const float we = w_edge[0], be = b_edge[0];
    const v4i* s4 = (const v4i*)src;
    const v4i* d4 = (const v4i*)dst;
    const v4f* e4 = (const v4f*)ea;
    for (int q = q0 + threadIdx.x; q < q1; q += P1_THR) {
        v4i s = __builtin_nontemporal_load(s4 + q);
        v4i d = __builtin_nontemporal_load(d4 + q);
        v4f e = __builtin_nontemporal_load(e4 + q);
        #pragma unroll
        for (int k = 0; k < 4; ++k) {
            int sv = (k == 0) ? s.x : (k == 1) ? s.y : (k == 2) ? s.z : s.w;
            int dv = (k == 0) ? d.x : (k == 1) ? d.y : (k == 2) ? d.z : d.w;
            float ev = (k == 0) ? e.x : (k == 1) ? e.y : (k == 2) ? e.z : e.w;
            int sb = sv / sbsz;
            int sl = sv - sb * sbsz;
            unsigned short tb = f2h(fmaf(ev, we, be));
            int p = atomicAdd(&cur8[sb], 1);       // LDS-only
            v2u r;
            r.x = ((unsigned)(sl & 0xFFFF) << 16) | (unsigned)tb;
            r.y = (unsigned)dv | ((unsigned)(sl >> 16) << 23);
            recs[p] = r;
        }
    }
}

// ---------------------------------------------------------------------------
// P2 v2: one chunk per block (sb = blk&7 -> XCD affinity, x slice L2-hot).
// 8-deep batched loads (MLP). LDS counting sort. Output to FIXED slot:
// pairs[(sb*CPS+cc)*CH] (fully coalesced uint4 dump) + u16 offset table.
// ZERO global atomics.
// ---------------------------------------------------------------------------
__global__ __launch_bounds__(P2_THR) void k_p2(
    const v2u* __restrict__ recs, const float* __restrict__ x,
    const int* __restrict__ sseg, int sbsz, int DB, int CPS,
    unsigned short* __restrict__ ofsT, unsigned* __restrict__ pairs)
{
    __shared__ __align__(16) unsigned pairbuf[CH];  // 32768 B
    __shared__ int hD[DBMAX];
    __shared__ int lofs[DBMAX];
    __shared__ int lcur[DBMAX];

    const int sb = blockIdx.x & 7;
    const int cc = blockIdx.x >> 3;
    const int seg0 = sseg[sb], seg1 = sseg[sb + 1];
    const int start = seg0 + cc * CH;
    if (start >= seg1) return;
    const int n = min(CH, seg1 - start);
    const float* xs = x + (size_t)sb * sbsz;
    const int tid = threadIdx.x;
    const int wid = tid >> 6, lane = tid & 63;

    for (int i = tid; i < DBMAX; i += P2_THR) hD[i] = 0;
    __syncthreads();

    // pass A: histogram, 8-deep batches
    #pragma unroll
    for (int half = 0; half < CH / (8 * P2_THR); ++half) {
        unsigned bk[8];
        #pragma unroll
        for (int k = 0; k < 8; ++k) {
            int idx = tid + (half * 8 + k) * P2_THR;
            bk[k] = (idx < n) ? ((recs[start + idx].y & 0x7FFFFFu) >> SHIFT)
                              : 0xFFFFu;
        }
        #pragma unroll
        for (int k = 0; k < 8; ++k)
            if (bk[k] != 0xFFFFu) atomicAdd(&hD[bk[k]], 1);
    }
    __syncthreads();

    // wave 0: exclusive scan of hD -> lofs
    if (wid == 0) {
        const int base = lane * (DBMAX / 64);
        int vals[DBMAX / 64];
        int s = 0;
        #pragma unroll
        for (int k = 0; k < DBMAX / 64; ++k) { vals[k] = s; s += hD[base + k]; }
        int excl = s;
        #pragma unroll
        for (int d = 1; d < 64; d <<= 1) {
            int t = __shfl_up(excl, d, 64);
            if (lane >= d) excl += t;
        }
        excl -= s;
        #pragma unroll
        for (int k = 0; k < DBMAX / 64; ++k) lofs[base + k] = vals[k] + excl;
    }
    __syncthreads();

    // offset table write + local cursors (no global reservation)
    const size_t tbase = (size_t)(sb * CPS + cc) * (DBMAX + 1);
    for (int b = tid; b < DB; b += P2_THR) {
        lcur[b] = lofs[b];
        ofsT[tbase + b] = (unsigned short)lofs[b];
    }
    if (tid == 0) ofsT[tbase + DB] = (unsigned short)n;
    __syncthreads();

    // pass B: 8-deep batched load + gather, then LDS scatter-sort
    #pragma unroll
    for (int half = 0; half < CH / (8 * P2_THR); ++half) {
        v2u r[8];
        #pragma unroll
        for (int k = 0; k < 8; ++k) {
            int idx = tid + (half * 8 + k) * P2_THR;
            if (idx < n) r[k] = recs[start + idx];
            else { r[k].x = 0u; r[k].y = 0u; }
        }
        float xv[8];
        #pragma unroll
        for (int k = 0; k < 8; ++k) {
            int sl = (int)(r[k].x >> 16) | (int)((r[k].y >> 23) << 16);
            xv[k] = xs[sl];
        }
        #pragma unroll
        for (int k = 0; k < 8; ++k) {
            int idx = tid + (half * 8 + k) * P2_THR;
            if (idx < n) {
                unsigned d = r[k].y & 0x7FFFFFu;
                float m = xv[k] * h2f((unsigned short)(r[k].x & 0xFFFFu));
                int li = atomicAdd(&lcur[d >> SHIFT], 1);
                pairbuf[li] = ((d & (SLICE - 1)) << 16) | (unsigned)f2h(m);
            }
        }
    }
    __syncthreads();

    // pass C: fully-coalesced uint4 dump into the chunk's fixed slot
    const size_t pbase = (size_t)(sb * CPS + cc) * CH;
    uint4* out4 = reinterpret_cast<uint4*>(pairs + pbase);
    const uint4* pb4 = reinterpret_cast<const uint4*>(pairbuf);
    #pragma unroll
    for (int i = 0; i < CH / 4 / P2_THR; ++i)
        out4[tid + i * P2_THR] = pb4[tid + i * P2_THR];
}

// ---------------------------------------------------------------------------
// binB v2: per-bucket block walks all chunks' runs via ofsT; LDS accumulate;
// fused root transform -> nodes.
// ---------------------------------------------------------------------------
__global__ __launch_bounds__(1024) void k_binB(
    const unsigned* __restrict__ pairs,
    const unsigned short* __restrict__ ofsT,
    const int* __restrict__ sseg, int CPS,
    const float* __restrict__ x,
    const float* __restrict__ w_root, const float* __restrict__ b_conv,
    float* __restrict__ nodes, int N)
{
    __shared__ float slice[SLICE];               // 65536 B
    const int b = blockIdx.x;
    for (int i = threadIdx.x; i < SLICE; i += 1024) slice[i] = 0.0f;
    __syncthreads();
    const int wid = threadIdx.x >> 6, lane = threadIdx.x & 63;
    for (int sb = 0; sb < NSB; ++sb) {
        const int len = sseg[sb + 1] - sseg[sb];
        const int ncc = (len + CH - 1) / CH;
        for (int cc = wid; cc < ncc; cc += 16) {
            const int g = sb * CPS + cc;
            const size_t tb = (size_t)g * (DBMAX + 1);
            const int o0 = ofsT[tb + b];
            const int o1 = ofsT[tb + b + 1];
            const unsigned* pc = pairs + (size_t)g * CH;
            for (int j = o0 + lane; j < o1; j += 64) {
                unsigned p = pc[j];
                atomicAdd(&slice[p >> 16], h2f((unsigned short)(p & 0xFFFFu)));
            }
        }
    }
    __syncthreads();
    const float wr = w_root[0], bc = b_conv[0];
    const int gbase = b << SHIFT;
    for (int i = threadIdx.x; i < SLICE; i += 1024) {
        int gi = gbase + i;
        if (gi < N) nodes[gi] = slice[i] + fmaf(__builtin_nontemporal_load(x + gi), wr, bc);
    }
}

// ---------------------------------------------------------------------------
// Mid-fallback: dst-binning with gather (reservation-based) + linear binB
// ---------------------------------------------------------------------------
__global__ __launch_bounds__(512) void k_count_mid(
    const int* __restrict__ dst, int nquads, int qpb, int DB,
    int* __restrict__ gcntD)
{
    __shared__ int hD[DBMAX];
    for (int i = threadIdx.x; i < DB; i += 512) hD[i] = 0;
    __syncthreads();
    const int q0 = blockIdx.x * qpb;
    const int q1 = min(q0 + qpb, nquads);
    const v4i* d4 = (const v4i*)dst;
    for (int q = q0 + threadIdx.x; q < q1; q += 512) {
        v4i d = __builtin_nontemporal_load(d4 + q);
        atomicAdd(&hD[d.x >> SHIFT], 1);
        atomicAdd(&hD[d.y >> SHIFT], 1);
        atomicAdd(&hD[d.z >> SHIFT], 1);
        atomicAdd(&hD[d.w >> SHIFT], 1);
    }
    __syncthreads();
    for (int i = threadIdx.x; i < DB; i += 512)
        if (hD[i]) atomicAdd(&gcntD[i], hD[i]);
}

__global__ void k_scanD(const int* __restrict__ gcntD, int DB,
                        int* __restrict__ bbaseD, int* __restrict__ gcurD)
{
    if (threadIdx.x == 0 && blockIdx.x == 0) {
        int run = 0;
        for (int i = 0; i < DB; ++i) { bbaseD[i] = run; gcurD[i] = run; run += gcntD[i]; }
        bbaseD[DB] = run;
    }
}

__global__ __launch_bounds__(512) void k_binA_resv(
    const float* __restrict__ x,
    const int* __restrict__ src, const int* __restrict__ dst,
    const float* __restrict__ ea,
    const float* __restrict__ w_edge, const float* __restrict__ b_edge,
    int nquads, int qpb, int DB,
    int* __restrict__ gcurD, unsigned* __restrict__ pairs)
{
    __shared__ int hD[DBMAX];
    __shared__ int cur[DBMAX];
    const int q0 = blockIdx.x * qpb;
    const int q1 = min(q0 + qpb, nquads);
    for (int i = threadIdx.x; i < DB; i += 512) hD[i] = 0;
    __syncthreads();
    const v4i* s4 = (const v4i*)src;
    const v4i* d4 = (const v4i*)dst;
    const v4f* e4 = (const v4f*)ea;
    for (int q = q0 + threadIdx.x; q < q1; q += 512) {
        v4i d = d4[q];
        atomicAdd(&hD[d.x >> SHIFT], 1);
        atomicAdd(&hD[d.y >> SHIFT], 1);
        atomicAdd(&hD[d.z >> SHIFT], 1);
        atomicAdd(&hD[d.w >> SHIFT], 1);
    }
    __syncthreads();
    for (int i = threadIdx.x; i < DB; i += 512) {
        int cnt = hD[i];
        cur[i] = cnt ? atomicAdd(&gcurD[i], cnt) : 0;
    }
    __syncthreads();
    const float we = w_edge[0], be = b_edge[0];
    for (int q = q0 + threadIdx.x; q < q1; q += 512) {
        v4i s = __builtin_nontemporal_load(s4 + q);
        v4i d = d4[q];
        v4f e = __builtin_nontemporal_load(e4 + q);
        #pragma unroll
        for (int k = 0; k < 4; ++k) {
            int sv = (k == 0) ? s.x : (k == 1) ? s.y : (k == 2) ? s.z : s.w;
            unsigned dv = (unsigned)((k == 0) ? d.x : (k == 1) ? d.y : (k == 2) ? d.z : d.w);
            float ev = (k == 0) ? e.x : (k == 1) ? e.y : (k == 2) ? e.z : e.w;
            float m = x[sv] * fmaf(ev, we, be);
            int p = atomicAdd(&cur[dv >> SHIFT], 1);
            pairs[p] = ((dv & (SLICE - 1)) << 16) | (unsigned)f2h(m);
        }
    }
}

__global__ __launch_bounds__(1024) void k_binB_lin(
    const unsigned* __restrict__ pairs,
    const int* __restrict__ bbaseD,
    const float* __restrict__ x,
    const float* __restrict__ w_root, const float* __restrict__ b_conv,
    float* __restrict__ nodes, int N)
{
    __shared__ float slice[SLICE];
    const int b = blockIdx.x;
    for (int i = threadIdx.x; i < SLICE; i += 1024) slice[i] = 0.0f;
    __syncthreads();
    const int p0 = bbaseD[b];
    const int p1 = bbaseD[b + 1];
    for (int i = p0 + threadIdx.x; i < p1; i += 1024) {
        unsigned p = __builtin_nontemporal_load(pairs + i);
        atomicAdd(&slice[p >> 16], h2f((unsigned short)(p & 0xFFFFu)));
    }
    __syncthreads();
    const float wr = w_root[0], bc = b_conv[0];
    const int gbase = b << SHIFT;
    for (int i = threadIdx.x; i < SLICE; i += 1024) {
        int gi = gbase + i;
        if (gi < N) nodes[gi] = slice[i] + fmaf(__builtin_nontemporal_load(x + gi), wr, bc);
    }
}

// ---------------------------------------------------------------------------
// Bottom fallback: global atomics
// ---------------------------------------------------------------------------
__global__ __launch_bounds__(256) void edge_kernel_atomic(
    const float* __restrict__ x,
    const int*   __restrict__ src, const int* __restrict__ dst,
    const float* __restrict__ ea,
    const float* __restrict__ w_edge, const float* __restrict__ b_edge,
    float* __restrict__ agg, int E)
{
    const float we = w_edge[0], be = b_edge[0];
    int tid = blockIdx.x * blockDim.x + threadIdx.x;
    int stride = gridDim.x * blockDim.x;
    for (int i = tid; i < E; i += stride)
        atomicAdd(&agg[dst[i]], x[src[i]] * fmaf(ea[i], we, be));
}

__global__ __launch_bounds__(256) void finalize_nodes(
    const float* __restrict__ x, const float* __restrict__ agg,
    const float* __restrict__ w_root, const float* __restrict__ b_conv,
    float* __restrict__ nodes, int N)
{
    const float wr = w_root[0], bc = b_conv[0];
    int i = blockIdx.x * blockDim.x + threadIdx.x;
    int stride = gridDim.x * blockDim.x;
    for (; i < N; i += stride) nodes[i] = agg[i] + fmaf(x[i], wr, bc);
}

// ---------------------------------------------------------------------------
// Head MLP over per-graph node vectors + softmax
// ---------------------------------------------------------------------------
__global__ __launch_bounds__(HEAD_BLK) void head_kernel(
    const float* __restrict__ nodes,
    const float* __restrict__ W1, const float* __restrict__ b1,
    const float* __restrict__ W2, const float* __restrict__ b2,
    const float* __restrict__ W3, const float* __restrict__ b3,
    float* __restrict__ out, int G)
{
    __shared__ float s_nodes[HEAD_BLK * NPG];   // 38912 B
    __shared__ float s_W1[NPG * 4];
    __shared__ float s_W2[4 * 4];
    __shared__ float s_W3[4 * 12];
    __shared__ float s_b1[4];
    __shared__ float s_b2[4];
    __shared__ float s_b3[12];

    const int tid = threadIdx.x;
    if (tid < NPG * 4) s_W1[tid] = W1[tid];
    if (tid >= 160 && tid < 176) s_W2[tid - 160] = W2[tid - 160];
    if (tid >= 176 && tid < 224) s_W3[tid - 176] = W3[tid - 176];
    if (tid >= 224 && tid < 228) s_b1[tid - 224] = b1[tid - 224];
    if (tid >= 228 && tid < 232) s_b2[tid - 228] = b2[tid - 228];
    if (tid >= 232 && tid < 244) s_b3[tid - 232] = b3[tid - 232];

    const int g0 = blockIdx.x * HEAD_BLK;
    const size_t ebase = (size_t)g0 * NPG;
    const int nelem = HEAD_BLK * NPG;
    const int avail = min(nelem, (G - g0) * NPG);
    for (int i = tid; i < avail; i += HEAD_BLK) s_nodes[i] = nodes[ebase + i];
    __syncthreads();

    const int g = g0 + tid;
    if (g >= G) return;
    const float* nd = &s_nodes[tid * NPG];

    float h1[4];
    #pragma unroll
    for (int k = 0; k < 4; ++k) h1[k] = s_b1[k];
    #pragma unroll
    for (int j = 0; j < NPG; ++j) {
        const float nj = nd[j];
        #pragma unroll
        for (int k = 0; k < 4; ++k) h1[k] = fmaf(nj, s_W1[j * 4 + k], h1[k]);
    }
    #pragma unroll
    for (int k = 0; k < 4; ++k) h1[k] = h1[k] >= 0.0f ? h1[k] : 0.01f * h1[k];

    float h2[4];
    #pragma unroll
    for (int k = 0; k < 4; ++k) {
        float a = s_b2[k];
        #pragma unroll
        for (int j = 0; j < 4; ++j) a = fmaf(h1[j], s_W2[j * 4 + k], a);
        h2[k] = a >= 0.0f ? a : 0.01f * a;
    }

    float h3[12];
    #pragma unroll
    for (int k = 0; k < 12; ++k) {
        float a = s_b3[k];
        #pragma unroll
        for (int j = 0; j < 4; ++j) a = fmaf(h2[j], s_W3[j * 12 + k], a);
        h3[k] = a >= 0.0f ? a : 0.01f * a;
    }

    float m = h3[0];
    #pragma unroll
    for (int k = 1; k < 12; ++k) m = fmaxf(m, h3[k]);
    float sum = 0.0f;
    #pragma unroll
    for (int k = 0; k < 12; ++k) { h3[k] = expf(h3[k] - m); sum += h3[k]; }
    const float inv = 1.0f / sum;

    float4* o = reinterpret_cast<float4*>(out + (size_t)g * 12);
    o[0] = make_float4(h3[0] * inv, h3[1] * inv, h3[2]  * inv, h3[3]  * inv);
    o[1] = make_float4(h3[4] * inv, h3[5] * inv, h3[6]  * inv, h3[7]  * inv);
    o[2] = make_float4(h3[8] * inv, h3[9] * inv, h3[10] * inv, h3[11] * inv);
}

extern "C" void kernel_launch(void* const* d_in, const int* in_sizes, int n_in,
                              void* d_out, int out_size, void* d_ws, size_t ws_size,
                              hipStream_t stream)
{
    const float* x      = (const float*)d_in[0];
    const int*   eidx   = (const int*)  d_in[1];
    const float* ea     = (const float*)d_in[2];
    const float* w_edge = (const float*)d_in[3];
    const float* b_edge = (const float*)d_in[4];
    const float* w_root = (const float*)d_in[5];
    const float* b_conv = (const float*)d_in[6];
    const float* W1 = (const float*)d_in[7];
    const float* b1 = (const float*)d_in[8];
    const float* W2 = (const float*)d_in[9];
    const float* b2 = (const float*)d_in[10];
    const float* W3 = (const float*)d_in[11];
    const float* b3 = (const float*)d_in[12];
    float* out = (float*)d_out;

    const int N = in_sizes[0];
    const int E = in_sizes[2];
    const int G = N / NPG;
    const int* src = eidx;
    const int* dst = eidx + E;
    const int nquads = E / 4;
    const int DB = (N + SLICE - 1) >> SHIFT;

    const int hblocks = (G + HEAD_BLK - 1) / HEAD_BLK;
    char* ws = (char*)d_ws;

    const bool quadok = (E % 4) == 0 && DB <= DBMAX && DB >= 1;
    const int  sbsz   = (N % NSB == 0) ? (N / NSB) : 0;

    // chunks per super (with generous slack for super-count skew)
    const int CPS = ((E + NSB - 1) / NSB + 32768 + CH - 1) / CH;
    const size_t NCHG = (size_t)NSB * CPS;

    // meta ints: histM8[NSB*NB1] | sseg[NSB+1] | gcntD[DBMAX] | gcurD[DBMAX] |
    //            bbaseD[DBMAX+1]
    const size_t META_INTS = (size_t)NSB * NB1 + (NSB + 1) + DBMAX + DBMAX + (DBMAX + 1);

    // v4 layout: recs (E*8) | pairs (NCHG*CH*4) | ofsT (NCHG*(DBMAX+1)*2) |
    //            nodes (N*4) | meta
    size_t off_pairs = (size_t)E * 8;
    size_t sz_pairs  = NCHG * CH * 4;
    size_t off_ofsT  = off_pairs + sz_pairs;
    size_t sz_ofsT   = (NCHG * (DBMAX + 1) * 2 + 15) & ~(size_t)15;
    size_t off_nodes = off_ofsT + sz_ofsT;
    size_t off_meta  = off_nodes + (size_t)N * 4;
    size_t need_v4   = off_meta + META_INTS * 4;

    // mid layout: pairs (E*4) | nodes | meta
    size_t off_nodes_mid = (size_t)E * 4;
    size_t off_meta_mid  = off_nodes_mid + (size_t)N * 4;
    size_t need_mid      = off_meta_mid + META_INTS * 4;

    if (quadok && sbsz > 0 && need_v4 <= ws_size) {
        v2u*            recs  = (v2u*)ws;
        unsigned*       pairs = (unsigned*)(ws + off_pairs);
        unsigned short* ofsT  = (unsigned short*)(ws + off_ofsT);
        float*          nodes = (float*)(ws + off_nodes);
        int*            meta  = (int*)(ws + off_meta);
        int* histM8 = meta;
        int* sseg   = meta + NSB * NB1;

        const int qpb = (nquads + NB1 - 1) / NB1;
        k_p1a<<<NB1, P1_THR, 0, stream>>>(src, nquads, qpb, sbsz, histM8);
        k_scanM<<<1, 512, 0, stream>>>(histM8, sseg);
        k_p1b<<<NB1, P1_THR, 0, stream>>>(src, dst, ea, w_edge, b_edge,
                                          nquads, qpb, sbsz, histM8, recs);
        k_p2<<<NSB * CPS, P2_THR, 0, stream>>>(recs, x, sseg, sbsz, DB, CPS,
                                               ofsT, pairs);
        k_binB<<<DB, 1024, 0, stream>>>(pairs, ofsT, sseg, CPS, x,
                                        w_root, b_conv, nodes, N);
        head_kernel<<<hblocks, HEAD_BLK, 0, stream>>>(nodes, W1, b1, W2, b2,
                                                      W3, b3, out, G);
    } else if (quadok && need_mid <= ws_size) {
        unsigned* pairs = (unsigned*)ws;
        float*    nodes = (float*)(ws + off_nodes_mid);
        int*      meta  = (int*)(ws + off_meta_mid);
        int* gcntD  = meta + NSB * NB1 + (NSB + 1);
        int* gcurD  = gcntD + DBMAX;
        int* bbaseD = gcurD + DBMAX;

        hipMemsetAsync(gcntD, 0, DBMAX * sizeof(int), stream);
        const int NBm = 2048;
        const int qpbm = (nquads + NBm - 1) / NBm;
        k_count_mid<<<NBm, 512, 0, stream>>>(dst, nquads, qpbm, DB, gcntD);
        k_scanD<<<1, 64, 0, stream>>>(gcntD, DB, bbaseD, gcurD);
        k_binA_resv<<<NBm, 512, 0, stream>>>(x, src, dst, ea, w_edge, b_edge,
                                             nquads, qpbm, DB, gcurD, pairs);
        k_binB_lin<<<DB, 1024, 0, stream>>>(pairs, bbaseD, x, w_root, b_conv,
                                            nodes, N);
        head_kernel<<<hblocks, HEAD_BLK, 0, stream>>>(nodes, W1, b1, W2, b2,
                                                      W3, b3, out, G);
    } else {
        float* agg   = (float*)d_ws;
        float* nodes = agg + N;
        hipMemsetAsync(agg, 0, (size_t)N * sizeof(float), stream);
        edge_kernel_atomic<<<2048, 256, 0, stream>>>(x, src, dst, ea, w_edge,
                                                     b_edge, agg, E);
        finalize_nodes<<<2048, 256, 0, stream>>>(x, agg, w_root, b_conv, nodes, N);
        head_kernel<<<hblocks, HEAD_BLK, 0, stream>>>(nodes, W1, b1, W2, b2,
                                                      W3, b3, out, G);
    }
}

// Round 14
// 1099.466 us; speedup vs baseline: 1.1412x; 1.0657x over previous
//
#include <hip/hip_runtime.h>
#include <hip/hip_fp16.h>

#define NPG 38
#define HEAD_BLK 256
#define SHIFT 13
#define SLICE (1 << SHIFT)        // 8192 nodes per dst-bucket (32KB LDS in binB)
#define DBMAX 640                 // max dst buckets
#define NSB 8                     // src super-buckets (== XCD count)
#define NB1 1024                  // blocks for P1a/P1b
#define P1_THR 512
#define CH 8192                   // records per P2 chunk
#define P2_THR 512
#define BB_THR 1024
#define BB_PH 1024                // chunks staged per binB phase

typedef int      v4i __attribute__((ext_vector_type(4)));
typedef float    v4f __attribute__((ext_vector_type(4)));
typedef unsigned v2u __attribute__((ext_vector_type(2)));

static inline __device__ unsigned short f2h(float f) {
    return __half_as_ushort(__float2half(f));
}
static inline __device__ float h2f(unsigned short b) {
    return __half2float(__ushort_as_half(b));
}

// ---------------------------------------------------------------------------
// P1a: per-block per-super counts only (src read only; plain stores).
// ---------------------------------------------------------------------------
__global__ __launch_bounds__(P1_THR) void k_p1a(
    const int* __restrict__ src, int nquads, int qpb, int sbsz,
    int* __restrict__ histM8)          // [NSB][NB1]
{
    __shared__ int h8[NSB];
    const int tid = threadIdx.x;
    if (tid < NSB) h8[tid] = 0;
    __syncthreads();
    const int blk = blockIdx.x;
    const int q0 = blk * qpb;
    const int q1 = min(q0 + qpb, nquads);
    const v4i* s4 = (const v4i*)src;
    for (int q = q0 + tid; q < q1; q += P1_THR) {
        v4i s = __builtin_nontemporal_load(s4 + q);
        atomicAdd(&h8[s.x / sbsz], 1);
        atomicAdd(&h8[s.y / sbsz], 1);
        atomicAdd(&h8[s.z / sbsz], 1);
        atomicAdd(&h8[s.w / sbsz], 1);
    }
    __syncthreads();
    if (tid < NSB) histM8[tid * NB1 + blk] = h8[tid];
}

// ---------------------------------------------------------------------------
// scanM: histM8 -> absolute per-(super,block) emit offsets (in place) + sseg.
// ---------------------------------------------------------------------------
__global__ __launch_bounds__(512) void k_scanM(
    int* __restrict__ histM8, int* __restrict__ sseg)
{
    __shared__ int stot[NSB];
    __shared__ int sbase[NSB + 1];
    const int tid = threadIdx.x;
    const int wid = tid >> 6, lane = tid & 63;

    const int base = wid * NB1 + lane * (NB1 / 64);
    int vals[NB1 / 64];
    int s = 0;
    #pragma unroll
    for (int k = 0; k < NB1 / 64; ++k) { vals[k] = s; s += histM8[base + k]; }
    int excl = s;
    #pragma unroll
    for (int d = 1; d < 64; d <<= 1) {
        int t = __shfl_up(excl, d, 64);
        if (lane >= d) excl += t;
    }
    excl -= s;
    if (lane == 63) stot[wid] = excl + s;
    __syncthreads();
    if (tid == 0) {
        int run = 0;
        for (int i = 0; i < NSB; ++i) { sbase[i] = run; run += stot[i]; }
        sbase[NSB] = run;
    }
    __syncthreads();
    const int b0 = sbase[wid] + excl;
    #pragma unroll
    for (int k = 0; k < NB1 / 64; ++k) histM8[base + k] = vals[k] + b0;
    if (tid < NSB + 1) sseg[tid] = sbase[tid];
}

// ---------------------------------------------------------------------------
// P1b: re-read edges, emit records at precomputed absolute offsets.
// Record = 8B: lo = (src_local[15:0]<<16)|fp16(theta), hi = dst|(sl>>16)<<23
// ---------------------------------------------------------------------------
__global__ __launch_bounds__(P1_THR) void k_p1b(
    const int* __restrict__ src, const int* __restrict__ dst,
    const float* __restrict__ ea,
    const float* __restrict__ w_edge, const float* __restrict__ b_edge,
    int nquads, int qpb, int sbsz,
    const int* __restrict__ histM8,
    v2u* __restrict__ recs)
{
    __shared__ int cur8[NSB];
    const int blk = blockIdx.x;
    if (threadIdx.x < NSB) cur8[threadIdx.x] = histM8[threadIdx.x * NB1 + blk];
    __syncthreads();
    const int q0 = blk * qpb;
    const int q1 = min(q0 + qpb, nquads);
    const float we = w_edge[0], be = b_edge[0];
    const v4i* s4 = (const v4i*)src;
    const v4i* d4 = (const v4i*)dst;
    const v4f* e4 = (const v4f*)ea;
    for (int q = q0 + threadIdx.x; q < q1; q += P1_THR) {
        v4i s = __builtin_nontemporal_load(s4 + q);
        v4i d = __builtin_nontemporal_load(d4 + q);
        v4f e = __builtin_nontemporal_load(e4 + q);
        #pragma unroll
        for (int k = 0; k < 4; ++k) {
            int sv = (k == 0) ? s.x : (k == 1) ? s.y : (k == 2) ? s.z : s.w;
            int dv = (k == 0) ? d.x : (k == 1) ? d.y : (k == 2) ? d.z : d.w;
            float ev = (k == 0) ? e.x : (k == 1) ? e.y : (k == 2) ? e.z : e.w;
            int sb = sv / sbsz;
            int sl = sv - sb * sbsz;
            unsigned short tb = f2h(fmaf(ev, we, be));
            int p = atomicAdd(&cur8[sb], 1);       // LDS-only
            v2u r;
            r.x = ((unsigned)(sl & 0xFFFF) << 16) | (unsigned)tb;
            r.y = (unsigned)dv | ((unsigned)(sl >> 16) << 23);
            recs[p] = r;
        }
    }
}

// ---------------------------------------------------------------------------
// P2 v3: GLOBAL chunking (chunk j = recs[j*CH, j*CH+CH)); distribution-
// independent. Per-record super resolved against sseg (branchless). XCD
// swizzle keeps contiguous chunks (same super -> same x slice) on one XCD.
// LDS counting sort -> fixed slot pairs[(size_t)j*CH] + u16 offset table.
// ZERO global atomics.
// ---------------------------------------------------------------------------
__global__ __launch_bounds__(P2_THR) void k_p2(
    const v2u* __restrict__ recs, const float* __restrict__ x,
    const int* __restrict__ sseg, int sbsz, int DB, int NCH, int bpx, int E,
    unsigned short* __restrict__ ofsT, unsigned* __restrict__ pairs)
{
    __shared__ __align__(16) unsigned pairbuf[CH];  // 32768 B
    __shared__ int hD[DBMAX];
    __shared__ int lofs[DBMAX];
    __shared__ int lcur[DBMAX];
    __shared__ int sS[NSB + 1];

    const int jraw = blockIdx.x;
    const int j = (jraw & 7) * bpx + (jraw >> 3);   // XCD-affine, bijective
    if (j >= NCH) return;
    const int start = j * CH;
    const int n = min(CH, E - start);
    const int tid = threadIdx.x;
    const int wid = tid >> 6, lane = tid & 63;

    if (tid < NSB + 1) sS[tid] = sseg[tid];
    for (int i = tid; i < DBMAX; i += P2_THR) hD[i] = 0;
    __syncthreads();

    // pass A: histogram, 8-deep batches
    #pragma unroll
    for (int half = 0; half < CH / (8 * P2_THR); ++half) {
        unsigned bk[8];
        #pragma unroll
        for (int k = 0; k < 8; ++k) {
            int idx = tid + (half * 8 + k) * P2_THR;
            bk[k] = (idx < n) ? ((recs[start + idx].y & 0x7FFFFFu) >> SHIFT)
                              : 0xFFFFu;
        }
        #pragma unroll
        for (int k = 0; k < 8; ++k)
            if (bk[k] != 0xFFFFu) atomicAdd(&hD[bk[k]], 1);
    }
    __syncthreads();

    // wave 0: exclusive scan of hD -> lofs (10 elems/lane)
    if (wid == 0) {
        const int base = lane * (DBMAX / 64);
        int vals[DBMAX / 64];
        int s = 0;
        #pragma unroll
        for (int k = 0; k < DBMAX / 64; ++k) { vals[k] = s; s += hD[base + k]; }
        int excl = s;
        #pragma unroll
        for (int d = 1; d < 64; d <<= 1) {
            int t = __shfl_up(excl, d, 64);
            if (lane >= d) excl += t;
        }
        excl -= s;
        #pragma unroll
        for (int k = 0; k < DBMAX / 64; ++k) lofs[base + k] = vals[k] + excl;
    }
    __syncthreads();

    // offset table write + local cursors
    const size_t tbase = (size_t)j * (DBMAX + 1);
    for (int b = tid; b < DB; b += P2_THR) {
        lcur[b] = lofs[b];
        ofsT[tbase + b] = (unsigned short)lofs[b];
    }
    if (tid == 0) ofsT[tbase + DB] = (unsigned short)n;
    __syncthreads();

    // pass B: 8-deep batched load + gather (x slice L2-hot), LDS scatter-sort
    #pragma unroll
    for (int half = 0; half < CH / (8 * P2_THR); ++half) {
        v2u r[8];
        #pragma unroll
        for (int k = 0; k < 8; ++k) {
            int idx = tid + (half * 8 + k) * P2_THR;
            if (idx < n) r[k] = recs[start + idx];
            else { r[k].x = 0u; r[k].y = 0u; }
        }
        float xv[8];
        #pragma unroll
        for (int k = 0; k < 8; ++k) {
            int idx = tid + (half * 8 + k) * P2_THR;
            int gp = start + min(idx, n - 1);
            int sbr = 0;
            #pragma unroll
            for (int s = 1; s < NSB; ++s) sbr += (gp >= sS[s]);
            int sl = (int)(r[k].x >> 16) | (int)((r[k].y >> 23) << 16);
            xv[k] = x[(size_t)sbr * sbsz + sl];
        }
        #pragma unroll
        for (int k = 0; k < 8; ++k) {
            int idx = tid + (half * 8 + k) * P2_THR;
            if (idx < n) {
                unsigned d = r[k].y & 0x7FFFFFu;
                float m = xv[k] * h2f((unsigned short)(r[k].x & 0xFFFFu));
                int li = atomicAdd(&lcur[d >> SHIFT], 1);
                pairbuf[li] = ((d & (SLICE - 1)) << 16) | (unsigned)f2h(m);
            }
        }
    }
    __syncthreads();

    // pass C: fully-coalesced uint4 dump into the chunk's fixed slot
    const size_t pbase = (size_t)j * CH;
    uint4* out4 = reinterpret_cast<uint4*>(pairs + pbase);
    const uint4* pb4 = reinterpret_cast<const uint4*>(pairbuf);
    #pragma unroll
    for (int i = 0; i < CH / 4 / P2_THR; ++i)
        out4[tid + i * P2_THR] = pb4[tid + i * P2_THR];
}

// ---------------------------------------------------------------------------
// binB v3: per-bucket block; 6 phases of <=1024 chunks. Stage (o0,len) into
// LDS, wave-0 prefix scan, then FLATTENED pair loop with LDS binary search:
// all 1024 lanes issue independent pairs loads each iteration (full MLP).
// ---------------------------------------------------------------------------
__global__ __launch_bounds__(BB_THR) void k_binB(
    const unsigned* __restrict__ pairs,
    const unsigned short* __restrict__ ofsT,
    int NCH, int DB,
    const float* __restrict__ x,
    const float* __restrict__ w_root, const float* __restrict__ b_conv,
    float* __restrict__ nodes, int N)
{
    __shared__ float slice[SLICE];               // 32768 B
    __shared__ unsigned short so0[BB_PH];        // 2048 B
    __shared__ int spre[BB_PH];                  // 4096 B
    __shared__ int sTot;
    const int b = blockIdx.x;
    const int tid = threadIdx.x;
    const int wid = tid >> 6, lane = tid & 63;

    for (int i = tid; i < SLICE; i += BB_THR) slice[i] = 0.0f;
    __syncthreads();

    for (int ch0 = 0; ch0 < NCH; ch0 += BB_PH) {
        const int nc = min(BB_PH, NCH - ch0);
        // stage run bounds (parallel, independent loads)
        for (int c = tid; c < nc; c += BB_THR) {
            const size_t tb = (size_t)(ch0 + c) * (DBMAX + 1);
            int o0 = ofsT[tb + b];
            int o1 = ofsT[tb + b + 1];
            so0[c] = (unsigned short)o0;
            spre[c] = o1 - o0;
        }
        __syncthreads();
        // wave 0: exclusive scan of spre[0..nc) in place (16 elems/lane)
        if (wid == 0) {
            const int base = lane * (BB_PH / 64);
            int vals[BB_PH / 64];
            int s = 0;
            #pragma unroll
            for (int k = 0; k < BB_PH / 64; ++k) {
                int idx = base + k;
                int t = (idx < nc) ? spre[idx] : 0;
                vals[k] = s; s += t;
            }
            int excl = s;
            #pragma unroll
            for (int d = 1; d < 64; d <<= 1) {
                int t = __shfl_up(excl, d, 64);
                if (lane >= d) excl += t;
            }
            excl -= s;
            #pragma unroll
            for (int k = 0; k < BB_PH / 64; ++k) {
                int idx = base + k;
                if (idx < nc) spre[idx] = vals[k] + excl;
            }
            if (lane == 63) sTot = excl + s;
        }
        __syncthreads();
        const int total = sTot;
        // flattened pair loop: binary search chunk, load, LDS accumulate
        for (int i = tid; i < total; i += BB_THR) {
            int lo = 0, hi = nc - 1;
            while (lo < hi) {
                int mid = (lo + hi + 1) >> 1;
                if (spre[mid] <= i) lo = mid; else hi = mid - 1;
            }
            int off = i - spre[lo];
            unsigned p = pairs[(size_t)(ch0 + lo) * CH + so0[lo] + off];
            atomicAdd(&slice[p >> 16], h2f((unsigned short)(p & 0xFFFFu)));
        }
        __syncthreads();
    }

    const float wr = w_root[0], bc = b_conv[0];
    const int gbase = b << SHIFT;
    for (int i = tid; i < SLICE; i += BB_THR) {
        int gi = gbase + i;
        if (gi < N) nodes[gi] = slice[i] + fmaf(__builtin_nontemporal_load(x + gi), wr, bc);
    }
}

// ---------------------------------------------------------------------------
// Mid-fallback: dst-binning with gather (reservation-based) + linear binB
// ---------------------------------------------------------------------------
__global__ __launch_bounds__(512) void k_count_mid(
    const int* __restrict__ dst, int nquads, int qpb, int DB,
    int* __restrict__ gcntD)
{
    __shared__ int hD[DBMAX];
    for (int i = threadIdx.x; i < DB; i += 512) hD[i] = 0;
    __syncthreads();
    const int q0 = blockIdx.x * qpb;
    const int q1 = min(q0 + qpb, nquads);
    const v4i* d4 = (const v4i*)dst;
    for (int q = q0 + threadIdx.x; q < q1; q += 512) {
        v4i d = __builtin_nontemporal_load(d4 + q);
        atomicAdd(&hD[d.x >> SHIFT], 1);
        atomicAdd(&hD[d.y >> SHIFT], 1);
        atomicAdd(&hD[d.z >> SHIFT], 1);
        atomicAdd(&hD[d.w >> SHIFT], 1);
    }
    __syncthreads();
    for (int i = threadIdx.x; i < DB; i += 512)
        if (hD[i]) atomicAdd(&gcntD[i], hD[i]);
}

__global__ void k_scanD(const int* __restrict__ gcntD, int DB,
                        int* __restrict__ bbaseD, int* __restrict__ gcurD)
{
    if (threadIdx.x == 0 && blockIdx.x == 0) {
        int run = 0;
        for (int i = 0; i < DB; ++i) { bbaseD[i] = run; gcurD[i] = run; run += gcntD[i]; }
        bbaseD[DB] = run;
    }
}

__global__ __launch_bounds__(512) void k_binA_resv(
    const float* __restrict__ x,
    const int* __restrict__ src, const int* __restrict__ dst,
    const float* __restrict__ ea,
    const float* __restrict__ w_edge, const float* __restrict__ b_edge,
    int nquads, int qpb, int DB,
    int* __restrict__ gcurD, unsigned* __restrict__ pairs)
{
    __shared__ int hD[DBMAX];
    __shared__ int cur[DBMAX];
    const int q0 = blockIdx.x * qpb;
    const int q1 = min(q0 + qpb, nquads);
    for (int i = threadIdx.x; i < DB; i += 512) hD[i] = 0;
    __syncthreads();
    const v4i* s4 = (const v4i*)src;
    const v4i* d4 = (const v4i*)dst;
    const v4f* e4 = (const v4f*)ea;
    for (int q = q0 + threadIdx.x; q < q1; q += 512) {
        v4i d = d4[q];
        atomicAdd(&hD[d.x >> SHIFT], 1);
        atomicAdd(&hD[d.y >> SHIFT], 1);
        atomicAdd(&hD[d.z >> SHIFT], 1);
        atomicAdd(&hD[d.w >> SHIFT], 1);
    }
    __syncthreads();
    for (int i = threadIdx.x; i < DB; i += 512) {
        int cnt = hD[i];
        cur[i] = cnt ? atomicAdd(&gcurD[i], cnt) : 0;
    }
    __syncthreads();
    const float we = w_edge[0], be = b_edge[0];
    for (int q = q0 + threadIdx.x; q < q1; q += 512) {
        v4i s = __builtin_nontemporal_load(s4 + q);
        v4i d = d4[q];
        v4f e = __builtin_nontemporal_load(e4 + q);
        #pragma unroll
        for (int k = 0; k < 4; ++k) {
            int sv = (k == 0) ? s.x : (k == 1) ? s.y : (k == 2) ? s.z : s.w;
            unsigned dv = (unsigned)((k == 0) ? d.x : (k == 1) ? d.y : (k == 2) ? d.z : d.w);
            float ev = (k == 0) ? e.x : (k == 1) ? e.y : (k == 2) ? e.z : e.w;
            float m = x[sv] * fmaf(ev, we, be);
            int p = atomicAdd(&cur[dv >> SHIFT], 1);
            pairs[p] = ((dv & (SLICE - 1)) << 16) | (unsigned)f2h(m);
        }
    }
}

__global__ __launch_bounds__(1024) void k_binB_lin(
    const unsigned* __restrict__ pairs,
    const int* __restrict__ bbaseD,
    const float* __restrict__ x,
    const float* __restrict__ w_root, const float* __restrict__ b_conv,
    float* __restrict__ nodes, int N)
{
    __shared__ float slice[SLICE];
    const int b = blockIdx.x;
    for (int i = threadIdx.x; i < SLICE; i += 1024) slice[i] = 0.0f;
    __syncthreads();
    const int p0 = bbaseD[b];
    const int p1 = bbaseD[b + 1];
    for (int i = p0 + threadIdx.x; i < p1; i += 1024) {
        unsigned p = __builtin_nontemporal_load(pairs + i);
        atomicAdd(&slice[p >> 16], h2f((unsigned short)(p & 0xFFFFu)));
    }
    __syncthreads();
    const float wr = w_root[0], bc = b_conv[0];
    const int gbase = b << SHIFT;
    for (int i = threadIdx.x; i < SLICE; i += 1024) {
        int gi = gbase + i;
        if (gi < N) nodes[gi] = slice[i] + fmaf(__builtin_nontemporal_load(x + gi), wr, bc);
    }
}

// ---------------------------------------------------------------------------
// Bottom fallback: global atomics
// ---------------------------------------------------------------------------
__global__ __launch_bounds__(256) void edge_kernel_atomic(
    const float* __restrict__ x,
    const int*   __restrict__ src, const int* __restrict__ dst,
    const float* __restrict__ ea,
    const float* __restrict__ w_edge, const float* __restrict__ b_edge,
    float* __restrict__ agg, int E)
{
    const float we = w_edge[0], be = b_edge[0];
    int tid = blockIdx.x * blockDim.x + threadIdx.x;
    int stride = gridDim.x * blockDim.x;
    for (int i = tid; i < E; i += stride)
        atomicAdd(&agg[dst[i]], x[src[i]] * fmaf(ea[i], we, be));
}

__global__ __launch_bounds__(256) void finalize_nodes(
    const float* __restrict__ x, const float* __restrict__ agg,
    const float* __restrict__ w_root, const float* __restrict__ b_conv,
    float* __restrict__ nodes, int N)
{
    const float wr = w_root[0], bc = b_conv[0];
    int i = blockIdx.x * blockDim.x + threadIdx.x;
    int stride = gridDim.x * blockDim.x;
    for (; i < N; i += stride) nodes[i] = agg[i] + fmaf(x[i], wr, bc);
}

// ---------------------------------------------------------------------------
// Head MLP over per-graph node vectors + softmax
// ---------------------------------------------------------------------------
__global__ __launch_bounds__(HEAD_BLK) void head_kernel(
    const float* __restrict__ nodes,
    const float* __restrict__ W1, const float* __restrict__ b1,
    const float* __restrict__ W2, const float* __restrict__ b2,
    const float* __restrict__ W3, const float* __restrict__ b3,
    float* __restrict__ out, int G)
{
    __shared__ float s_nodes[HEAD_BLK * NPG];   // 38912 B
    __shared__ float s_W1[NPG * 4];
    __shared__ float s_W2[4 * 4];
    __shared__ float s_W3[4 * 12];
    __shared__ float s_b1[4];
    __shared__ float s_b2[4];
    __shared__ float s_b3[12];

    const int tid = threadIdx.x;
    if (tid < NPG * 4) s_W1[tid] = W1[tid];
    if (tid >= 160 && tid < 176) s_W2[tid - 160] = W2[tid - 160];
    if (tid >= 176 && tid < 224) s_W3[tid - 176] = W3[tid - 176];
    if (tid >= 224 && tid < 228) s_b1[tid - 224] = b1[tid - 224];
    if (tid >= 228 && tid < 232) s_b2[tid - 228] = b2[tid - 228];
    if (tid >= 232 && tid < 244) s_b3[tid - 232] = b3[tid - 232];

    const int g0 = blockIdx.x * HEAD_BLK;
    const size_t ebase = (size_t)g0 * NPG;
    const int nelem = HEAD_BLK * NPG;
    const int avail = min(nelem, (G - g0) * NPG);
    for (int i = tid; i < avail; i += HEAD_BLK) s_nodes[i] = nodes[ebase + i];
    __syncthreads();

    const int g = g0 + tid;
    if (g >= G) return;
    const float* nd = &s_nodes[tid * NPG];

    float h1[4];
    #pragma unroll
    for (int k = 0; k < 4; ++k) h1[k] = s_b1[k];
    #pragma unroll
    for (int j = 0; j < NPG; ++j) {
        const float nj = nd[j];
        #pragma unroll
        for (int k = 0; k < 4; ++k) h1[k] = fmaf(nj, s_W1[j * 4 + k], h1[k]);
    }
    #pragma unroll
    for (int k = 0; k < 4; ++k) h1[k] = h1[k] >= 0.0f ? h1[k] : 0.01f * h1[k];

    float h2[4];
    #pragma unroll
    for (int k = 0; k < 4; ++k) {
        float a = s_b2[k];
        #pragma unroll
        for (int j = 0; j < 4; ++j) a = fmaf(h1[j], s_W2[j * 4 + k], a);
        h2[k] = a >= 0.0f ? a : 0.01f * a;
    }

    float h3[12];
    #pragma unroll
    for (int k = 0; k < 12; ++k) {
        float a = s_b3[k];
        #pragma unroll
        for (int j = 0; j < 4; ++j) a = fmaf(h2[j], s_W3[j * 12 + k], a);
        h3[k] = a >= 0.0f ? a : 0.01f * a;
    }

    float m = h3[0];
    #pragma unroll
    for (int k = 1; k < 12; ++k) m = fmaxf(m, h3[k]);
    float sum = 0.0f;
    #pragma unroll
    for (int k = 0; k < 12; ++k) { h3[k] = expf(h3[k] - m); sum += h3[k]; }
    const float inv = 1.0f / sum;

    float4* o = reinterpret_cast<float4*>(out + (size_t)g * 12);
    o[0] = make_float4(h3[0] * inv, h3[1] * inv, h3[2]  * inv, h3[3]  * inv);
    o[1] = make_float4(h3[4] * inv, h3[5] * inv, h3[6]  * inv, h3[7]  * inv);
    o[2] = make_float4(h3[8] * inv, h3[9] * inv, h3[10] * inv, h3[11] * inv);
}

extern "C" void kernel_launch(void* const* d_in, const int* in_sizes, int n_in,
                              void* d_out, int out_size, void* d_ws, size_t ws_size,
                              hipStream_t stream)
{
    const float* x      = (const float*)d_in[0];
    const int*   eidx   = (const int*)  d_in[1];
    const float* ea     = (const float*)d_in[2];
    const float* w_edge = (const float*)d_in[3];
    const float* b_edge = (const float*)d_in[4];
    const float* w_root = (const float*)d_in[5];
    const float* b_conv = (const float*)d_in[6];
    const float* W1 = (const float*)d_in[7];
    const float* b1 = (const float*)d_in[8];
    const float* W2 = (const float*)d_in[9];
    const float* b2 = (const float*)d_in[10];
    const float* W3 = (const float*)d_in[11];
    const float* b3 = (const float*)d_in[12];
    float* out = (float*)d_out;

    const int N = in_sizes[0];
    const int E = in_sizes[2];
    const int G = N / NPG;
    const int* src = eidx;
    const int* dst = eidx + E;
    const int nquads = E / 4;
    const int DB = (N + SLICE - 1) >> SHIFT;

    const int hblocks = (G + HEAD_BLK - 1) / HEAD_BLK;
    char* ws = (char*)d_ws;

    const bool quadok = (E % 4) == 0 && DB <= DBMAX && DB >= 1;
    const int  sbsz   = (N % NSB == 0) ? (N / NSB) : 0;

    const int NCH = (E + CH - 1) / CH;            // global chunk count
    const int bpx = (NCH + 7) / 8;

    // meta ints: histM8[NSB*NB1] | sseg[NSB+1] | gcntD[DBMAX] | gcurD[DBMAX] |
    //            bbaseD[DBMAX+1]
    const size_t META_INTS = (size_t)NSB * NB1 + (NSB + 1) + DBMAX + DBMAX + (DBMAX + 1);

    // v5 layout: recs (E*8) | pairs (NCH*CH*4) | ofsT (NCH*(DBMAX+1)*2) |
    //            nodes (N*4) | meta
    size_t off_pairs = (size_t)E * 8;
    size_t sz_pairs  = (size_t)NCH * CH * 4;
    size_t off_ofsT  = off_pairs + sz_pairs;
    size_t sz_ofsT   = ((size_t)NCH * (DBMAX + 1) * 2 + 15) & ~(size_t)15;
    size_t off_nodes = off_ofsT + sz_ofsT;
    size_t off_meta  = off_nodes + (size_t)N * 4;
    size_t need_v5   = off_meta + META_INTS * 4;

    // mid layout: pairs (E*4) | nodes | meta
    size_t off_nodes_mid = (size_t)E * 4;
    size_t off_meta_mid  = off_nodes_mid + (size_t)N * 4;
    size_t need_mid      = off_meta_mid + META_INTS * 4;

    if (quadok && sbsz > 0 && need_v5 <= ws_size) {
        v2u*            recs  = (v2u*)ws;
        unsigned*       pairs = (unsigned*)(ws + off_pairs);
        unsigned short* ofsT  = (unsigned short*)(ws + off_ofsT);
        float*          nodes = (float*)(ws + off_nodes);
        int*            meta  = (int*)(ws + off_meta);
        int* histM8 = meta;
        int* sseg   = meta + NSB * NB1;

        const int qpb = (nquads + NB1 - 1) / NB1;
        k_p1a<<<NB1, P1_THR, 0, stream>>>(src, nquads, qpb, sbsz, histM8);
        k_scanM<<<1, 512, 0, stream>>>(histM8, sseg);
        k_p1b<<<NB1, P1_THR, 0, stream>>>(src, dst, ea, w_edge, b_edge,
                                          nquads, qpb, sbsz, histM8, recs);
        k_p2<<<8 * bpx, P2_THR, 0, stream>>>(recs, x, sseg, sbsz, DB, NCH, bpx,
                                             E, ofsT, pairs);
        k_binB<<<DB, BB_THR, 0, stream>>>(pairs, ofsT, NCH, DB, x,
                                          w_root, b_conv, nodes, N);
        head_kernel<<<hblocks, HEAD_BLK, 0, stream>>>(nodes, W1, b1, W2, b2,
                                                      W3, b3, out, G);
    } else if (quadok && need_mid <= ws_size) {
        unsigned* pairs = (unsigned*)ws;
        float*    nodes = (float*)(ws + off_nodes_mid);
        int*      meta  = (int*)(ws + off_meta_mid);
        int* gcntD  = meta + NSB * NB1 + (NSB + 1);
        int* gcurD  = gcntD + DBMAX;
        int* bbaseD = gcurD + DBMAX;

        hipMemsetAsync(gcntD, 0, DBMAX * sizeof(int), stream);
        const int NBm = 2048;
        const int qpbm = (nquads + NBm - 1) / NBm;
        k_count_mid<<<NBm, 512, 0, stream>>>(dst, nquads, qpbm, DB, gcntD);
        k_scanD<<<1, 64, 0, stream>>>(gcntD, DB, bbaseD, gcurD);
        k_binA_resv<<<NBm, 512, 0, stream>>>(x, src, dst, ea, w_edge, b_edge,
                                             nquads, qpbm, DB, gcurD, pairs);
        k_binB_lin<<<DB, 1024, 0, stream>>>(pairs, bbaseD, x, w_root, b_conv,
                                            nodes, N);
        head_kernel<<<hblocks, HEAD_BLK, 0, stream>>>(nodes, W1, b1, W2, b2,
                                                      W3, b3, out, G);
    } else {
        float* agg   = (float*)d_ws;
        float* nodes = agg + N;
        hipMemsetAsync(agg, 0, (size_t)N * sizeof(float), stream);
        edge_kernel_atomic<<<2048, 256, 0, stream>>>(x, src, dst, ea, w_edge,
                                                     b_edge, agg, E);
        finalize_nodes<<<2048, 256, 0, stream>>>(x, agg, w_root, b_conv, nodes, N);
        head_kernel<<<hblocks, HEAD_BLK, 0, stream>>>(nodes, W1, b1, W2, b2,
                                                      W3, b3, out, G);
    }
}